// Round 1
// baseline (313.857 us; speedup 1.0000x reference)
//
#include <hip/hip_runtime.h>

// C2D_34419867910289 — fused categorical-attention block, bf16 MFMA version.
// scores = x @ Mt^T with Mt = (Wq @ K^T)/sqrt(D) precomputed (K = emb @ Wk).
// Pipeline per (j, 64-row b-tile): scores -> softmax -> @V -> +x,LN1 -> @W1,
// relu -> @W2 -> +h,LN2 -> sigmoid(h.Ws + bs).

typedef __attribute__((ext_vector_type(4))) float f32x4;
typedef __attribute__((ext_vector_type(8))) short bf16x8;

#define DEVI static __device__ __forceinline__

constexpr int NC = 32, D = 128, C = 256, H = 256, BT = 64;

DEVI unsigned short f2b(float f) {  // RN-even float -> bf16
  unsigned u = __builtin_bit_cast(unsigned, f);
  u += 0x7fffu + ((u >> 16) & 1u);
  return (unsigned short)(u >> 16);
}
DEVI float b2f(unsigned short h) {
  unsigned u = ((unsigned)h) << 16;
  return __builtin_bit_cast(float, u);
}

// ---------------- prep: K (fp32 tmp) and V^T (bf16) ----------------
__global__ __launch_bounds__(256) void kv_kernel(
    const float* __restrict__ emb, const float* __restrict__ Wk,
    const float* __restrict__ Wv, float* __restrict__ Ktmp,
    unsigned short* __restrict__ Vt) {
  __shared__ float wk[D][D];   // read wk[d][e], lanes e-consecutive: no pad
  __shared__ float wv[D][D];
  __shared__ float eb[32][D];  // broadcast reads
  const int j = blockIdx.x >> 3, ct = blockIdx.x & 7, tid = threadIdx.x;
  const float4* gk = (const float4*)(Wk + j * D * D);
  const float4* gv = (const float4*)(Wv + j * D * D);
  float4* lk = (float4*)&wk[0][0];
  float4* lv = (float4*)&wv[0][0];
  for (int i = tid; i < D * D / 4; i += 256) { lk[i] = gk[i]; lv[i] = gv[i]; }
  const float4* ge = (const float4*)(emb + (j * C + ct * 32) * D);
  float4* le = (float4*)&eb[0][0];
  for (int i = tid; i < 32 * D / 4; i += 256) le[i] = ge[i];
  __syncthreads();
  const int e = tid & 127, sel = tid >> 7;
  const float(*w)[D] = sel ? (const float(*)[D])wv : (const float(*)[D])wk;
  float acc[32];
#pragma unroll
  for (int r = 0; r < 32; ++r) acc[r] = 0.f;
  for (int d = 0; d < D; ++d) {
    float wde = w[d][e];
#pragma unroll
    for (int r = 0; r < 32; ++r) acc[r] = fmaf(eb[r][d], wde, acc[r]);
  }
  if (sel == 0) {
    for (int r = 0; r < 32; ++r) Ktmp[(j * C + ct * 32 + r) * D + e] = acc[r];
  } else {
    for (int r = 0; r < 32; ++r)
      Vt[(j * D + e) * C + ct * 32 + r] = f2b(acc[r]);
  }
}

// ---------------- prep: Mt[j][c][d] = (1/sqrt(D)) * sum_e Wq[d][e]K[c][e] ----
__global__ __launch_bounds__(256) void m_kernel(
    const float* __restrict__ Wq, const float* __restrict__ Ktmp,
    unsigned short* __restrict__ Mt) {
  __shared__ float wq[D][D + 1];  // read wq[d][e], lanes d-consecutive: pad
  __shared__ float kt[32][D];     // broadcast reads
  const int j = blockIdx.x >> 3, ct = blockIdx.x & 7, tid = threadIdx.x;
  for (int i = tid; i < D * D / 4; i += 256) {
    float4 v = ((const float4*)(Wq + j * D * D))[i];
    int r = (i * 4) / D, c = (i * 4) % D;
    wq[r][c] = v.x; wq[r][c + 1] = v.y; wq[r][c + 2] = v.z; wq[r][c + 3] = v.w;
  }
  for (int i = tid; i < 32 * D / 4; i += 256)
    ((float4*)&kt[0][0])[i] = ((const float4*)(Ktmp + (j * C + ct * 32) * D))[i];
  __syncthreads();
  const int d = tid & 127, half = tid >> 7;
  float acc[16];
#pragma unroll
  for (int r = 0; r < 16; ++r) acc[r] = 0.f;
  for (int e = 0; e < D; ++e) {
    float w = wq[d][e];
#pragma unroll
    for (int r = 0; r < 16; ++r) acc[r] = fmaf(kt[half * 16 + r][e], w, acc[r]);
  }
  const float scale = 0.08838834764831845f;  // 1/sqrt(128)
  for (int r = 0; r < 16; ++r)
    Mt[(j * C + ct * 32 + half * 16 + r) * D + d] = f2b(acc[r] * scale);
}

// ---------------- prep: transposed bf16 copies of W1, W2 ----------------
__global__ __launch_bounds__(256) void tr_kernel(
    const float* __restrict__ W1, const float* __restrict__ W2,
    unsigned short* __restrict__ W1t, unsigned short* __restrict__ W2t) {
  const int tot = NC * D * H;  // 1048576
  long idx = (long)blockIdx.x * 256 + threadIdx.x;
  if (idx < tot) {  // W1t[j][h][d] = W1[j][d][h]
    int j = idx >> 15, r = (idx >> 7) & 255, dcol = idx & 127;
    W1t[idx] = f2b(W1[(j * D + dcol) * H + r]);
  } else if (idx < 2L * tot) {  // W2t[j][e][hh] = W2[j][hh][e]
    long o = idx - tot;
    int j = (int)(o >> 15), e = (int)((o >> 8) & 127), hh = (int)(o & 255);
    W2t[o] = f2b(W2[(j * H + hh) * D + e]);
  }
}

// ---------------- fused main kernel ----------------
__global__ __launch_bounds__(256) void fused_kernel(
    const float* __restrict__ x, const unsigned short* __restrict__ Mt,
    const unsigned short* __restrict__ Vt, const unsigned short* __restrict__ W1t,
    const unsigned short* __restrict__ W2t, const float* __restrict__ b1,
    const float* __restrict__ b2, const float* __restrict__ g1,
    const float* __restrict__ be1, const float* __restrict__ g2,
    const float* __restrict__ be2, const float* __restrict__ Ws,
    const float* __restrict__ bs, float* __restrict__ out) {
  constexpr int XS = 136;   // x/h1 row stride (elems), 272B: 16B-aligned, 2-way banks
  constexpr int WS256 = 136;  // wbuf stride for [256][128] panels
  constexpr int WS128 = 280;  // wbuf stride for [128][256] panels (560B)
  constexpr int AS = 264;     // alpha/ff row stride (528B)
  __shared__ __align__(16) unsigned short xb[BT * XS];    // 17408 B
  __shared__ __align__(16) unsigned short h1b[BT * XS];   // 17408 B
  __shared__ __align__(16) unsigned short wb[35840];      // 71680 B
  __shared__ __align__(16) unsigned short al[BT * AS];    // 33792 B
  __shared__ __align__(16) float sv[1024];                // 4096 B
  const int j = blockIdx.x >> 6, bt = blockIdx.x & 63, b0 = bt * BT;
  const int tid = threadIdx.x;
  const int w = tid >> 6, l = tid & 63, lr = l & 15, lg = l >> 4;

  // stage x tile (fp32 -> bf16)
  for (int i = tid; i < BT * D / 4; i += 256) {
    int r = i >> 5, seg = i & 31;
    float4 v = ((const float4*)(x + ((long)(b0 + r) * NC + j) * D))[seg];
    ushort4 u;
    u.x = f2b(v.x); u.y = f2b(v.y); u.z = f2b(v.z); u.w = f2b(v.w);
    *(ushort4*)&xb[r * XS + seg * 4] = u;
  }
  // stage small vectors
  for (int i = tid; i < 1024; i += 256) {
    float v;
    if (i < 256) v = b1[j * H + i];
    else if (i < 384) v = b2[j * D + i - 256];
    else if (i < 512) v = g1[i - 384];
    else if (i < 640) v = be1[i - 512];
    else if (i < 768) v = g2[i - 640];
    else if (i < 896) v = be2[i - 768];
    else v = Ws[j * D + i - 896];
    sv[i] = v;
  }
  // stage Mt panel [256][128]
  {
    const uint4* src = (const uint4*)(Mt + (long)j * C * D);
    for (int i = tid; i < 4096; i += 256) {
      int r = i >> 4, seg = i & 15;
      *(uint4*)&wb[r * WS256 + seg * 8] = src[i];
    }
  }
  __syncthreads();

  // ---- scores = xb @ Mt^T  (64 rows x 256 cols) ----
  f32x4 sc[16];
#pragma unroll
  for (int t = 0; t < 16; ++t) sc[t] = (f32x4){0.f, 0.f, 0.f, 0.f};
#pragma unroll
  for (int kc = 0; kc < 4; ++kc) {
    bf16x8 a = *(const bf16x8*)&xb[(w * 16 + lr) * XS + kc * 32 + lg * 8];
#pragma unroll
    for (int ct = 0; ct < 16; ++ct) {
      bf16x8 b = *(const bf16x8*)&wb[(ct * 16 + lr) * WS256 + kc * 32 + lg * 8];
      sc[ct] = __builtin_amdgcn_mfma_f32_16x16x32_bf16(a, b, sc[ct], 0, 0, 0);
    }
  }
  // ---- softmax over 256 cols (rows live across the 16 lanes of group lg) ----
  float mx[4] = {-1e30f, -1e30f, -1e30f, -1e30f};
#pragma unroll
  for (int ct = 0; ct < 16; ++ct)
#pragma unroll
    for (int i = 0; i < 4; ++i) mx[i] = fmaxf(mx[i], sc[ct][i]);
#pragma unroll
  for (int m = 1; m < 16; m <<= 1)
#pragma unroll
    for (int i = 0; i < 4; ++i) mx[i] = fmaxf(mx[i], __shfl_xor(mx[i], m));
  float sm[4] = {0.f, 0.f, 0.f, 0.f};
#pragma unroll
  for (int ct = 0; ct < 16; ++ct)
#pragma unroll
    for (int i = 0; i < 4; ++i) {
      float e = __expf(sc[ct][i] - mx[i]);
      sc[ct][i] = e;
      sm[i] += e;
    }
#pragma unroll
  for (int m = 1; m < 16; m <<= 1)
#pragma unroll
    for (int i = 0; i < 4; ++i) sm[i] += __shfl_xor(sm[i], m);
  float inv[4];
#pragma unroll
  for (int i = 0; i < 4; ++i) inv[i] = 1.f / sm[i];
#pragma unroll
  for (int ct = 0; ct < 16; ++ct)
#pragma unroll
    for (int i = 0; i < 4; ++i)
      al[(w * 16 + lg * 4 + i) * AS + ct * 16 + lr] = f2b(sc[ct][i] * inv[i]);
  __syncthreads();

  // stage Vt panel [128][256]
  {
    const uint4* src = (const uint4*)(Vt + (long)j * D * C);
    for (int i = tid; i < 4096; i += 256) {
      int r = i >> 5, seg = i & 31;
      *(uint4*)&wb[r * WS128 + seg * 8] = src[i];
    }
  }
  __syncthreads();

  // ---- h = alpha @ V  (64 x 128) ----
  f32x4 ha[8];
#pragma unroll
  for (int t = 0; t < 8; ++t) ha[t] = (f32x4){0.f, 0.f, 0.f, 0.f};
#pragma unroll
  for (int kc = 0; kc < 8; ++kc) {
    bf16x8 a = *(const bf16x8*)&al[(w * 16 + lr) * AS + kc * 32 + lg * 8];
#pragma unroll
    for (int et = 0; et < 8; ++et) {
      bf16x8 b = *(const bf16x8*)&wb[(et * 16 + lr) * WS128 + kc * 32 + lg * 8];
      ha[et] = __builtin_amdgcn_mfma_f32_16x16x32_bf16(a, b, ha[et], 0, 0, 0);
    }
  }
  // ---- residual + LN1 (keep h1 in regs for LN2 residual) ----
  float hv[8][4];
  float s1[4] = {0.f, 0.f, 0.f, 0.f}, s2[4] = {0.f, 0.f, 0.f, 0.f};
#pragma unroll
  for (int et = 0; et < 8; ++et)
#pragma unroll
    for (int i = 0; i < 4; ++i) {
      int row = w * 16 + lg * 4 + i, col = et * 16 + lr;
      float v = ha[et][i] + b2f(xb[row * XS + col]);
      hv[et][i] = v;
      s1[i] += v;
      s2[i] += v * v;
    }
#pragma unroll
  for (int m = 1; m < 16; m <<= 1)
#pragma unroll
    for (int i = 0; i < 4; ++i) {
      s1[i] += __shfl_xor(s1[i], m);
      s2[i] += __shfl_xor(s2[i], m);
    }
  float mu[4], rs[4];
#pragma unroll
  for (int i = 0; i < 4; ++i) {
    mu[i] = s1[i] * (1.f / 128.f);
    float var = s2[i] * (1.f / 128.f) - mu[i] * mu[i];
    rs[i] = rsqrtf(var + 1e-5f);
  }
#pragma unroll
  for (int et = 0; et < 8; ++et)
#pragma unroll
    for (int i = 0; i < 4; ++i) {
      int col = et * 16 + lr;
      float hn = (hv[et][i] - mu[i]) * rs[i] * sv[384 + col] + sv[512 + col];
      hv[et][i] = hn;
      h1b[(w * 16 + lg * 4 + i) * XS + col] = f2b(hn);
    }
  __syncthreads();

  // stage W1t panel [256][128]
  {
    const uint4* src = (const uint4*)(W1t + (long)j * H * D);
    for (int i = tid; i < 4096; i += 256) {
      int r = i >> 4, seg = i & 15;
      *(uint4*)&wb[r * WS256 + seg * 8] = src[i];
    }
  }
  __syncthreads();

  // ---- ff1 = relu(h1 @ W1 + b1)  (64 x 256) ----
  f32x4 fa[16];
#pragma unroll
  for (int t = 0; t < 16; ++t) fa[t] = (f32x4){0.f, 0.f, 0.f, 0.f};
#pragma unroll
  for (int kc = 0; kc < 4; ++kc) {
    bf16x8 a = *(const bf16x8*)&h1b[(w * 16 + lr) * XS + kc * 32 + lg * 8];
#pragma unroll
    for (int ht = 0; ht < 16; ++ht) {
      bf16x8 b = *(const bf16x8*)&wb[(ht * 16 + lr) * WS256 + kc * 32 + lg * 8];
      fa[ht] = __builtin_amdgcn_mfma_f32_16x16x32_bf16(a, b, fa[ht], 0, 0, 0);
    }
  }
#pragma unroll
  for (int ht = 0; ht < 16; ++ht)
#pragma unroll
    for (int i = 0; i < 4; ++i) {
      int col = ht * 16 + lr;
      float r = fmaxf(fa[ht][i] + sv[col], 0.f);
      al[(w * 16 + lg * 4 + i) * AS + col] = f2b(r);
    }
  __syncthreads();

  // stage W2t panel [128][256]
  {
    const uint4* src = (const uint4*)(W2t + (long)j * D * H);
    for (int i = tid; i < 4096; i += 256) {
      int r = i >> 5, seg = i & 31;
      *(uint4*)&wb[r * WS128 + seg * 8] = src[i];
    }
  }
  __syncthreads();

  // ---- ff2 + residual + LN2 + sigmoid readout ----
  f32x4 oa[8];
#pragma unroll
  for (int t = 0; t < 8; ++t) oa[t] = (f32x4){0.f, 0.f, 0.f, 0.f};
#pragma unroll
  for (int kc = 0; kc < 8; ++kc) {
    bf16x8 a = *(const bf16x8*)&al[(w * 16 + lr) * AS + kc * 32 + lg * 8];
#pragma unroll
    for (int et = 0; et < 8; ++et) {
      bf16x8 b = *(const bf16x8*)&wb[(et * 16 + lr) * WS128 + kc * 32 + lg * 8];
      oa[et] = __builtin_amdgcn_mfma_f32_16x16x32_bf16(a, b, oa[et], 0, 0, 0);
    }
  }
  float t1[4] = {0.f, 0.f, 0.f, 0.f}, t2[4] = {0.f, 0.f, 0.f, 0.f};
#pragma unroll
  for (int et = 0; et < 8; ++et)
#pragma unroll
    for (int i = 0; i < 4; ++i) {
      int col = et * 16 + lr;
      float v = oa[et][i] + sv[256 + col] + hv[et][i];
      oa[et][i] = v;
      t1[i] += v;
      t2[i] += v * v;
    }
#pragma unroll
  for (int m = 1; m < 16; m <<= 1)
#pragma unroll
    for (int i = 0; i < 4; ++i) {
      t1[i] += __shfl_xor(t1[i], m);
      t2[i] += __shfl_xor(t2[i], m);
    }
  float lp[4] = {0.f, 0.f, 0.f, 0.f};
#pragma unroll
  for (int i = 0; i < 4; ++i) {
    float mu2 = t1[i] * (1.f / 128.f);
    float var = t2[i] * (1.f / 128.f) - mu2 * mu2;
    float rs2 = rsqrtf(var + 1e-5f);
#pragma unroll
    for (int et = 0; et < 8; ++et) {
      int col = et * 16 + lr;
      float h2 = (oa[et][i] - mu2) * rs2 * sv[640 + col] + sv[768 + col];
      lp[i] = fmaf(h2, sv[896 + col], lp[i]);
    }
  }
#pragma unroll
  for (int m = 1; m < 16; m <<= 1)
#pragma unroll
    for (int i = 0; i < 4; ++i) lp[i] += __shfl_xor(lp[i], m);
  if (lr == 0) {
    float bsj = bs[j];
#pragma unroll
    for (int i = 0; i < 4; ++i) {
      float sg = 1.f / (1.f + __expf(-(lp[i] + bsj)));
      out[(b0 + w * 16 + lg * 4 + i) * NC + j] = sg;
    }
  }
}

extern "C" void kernel_launch(void* const* d_in, const int* in_sizes, int n_in,
                              void* d_out, int out_size, void* d_ws,
                              size_t ws_size, hipStream_t stream) {
  (void)in_sizes; (void)n_in; (void)out_size; (void)ws_size;
  const float* cat = (const float*)d_in[1];
  const float* emb = (const float*)d_in[2];
  const float* Wq = (const float*)d_in[3];
  const float* Wk = (const float*)d_in[4];
  const float* Wv = (const float*)d_in[5];
  const float* g1 = (const float*)d_in[6];
  const float* be1 = (const float*)d_in[7];
  const float* W1 = (const float*)d_in[8];
  const float* b1 = (const float*)d_in[9];
  const float* W2 = (const float*)d_in[10];
  const float* b2 = (const float*)d_in[11];
  const float* g2 = (const float*)d_in[12];
  const float* be2 = (const float*)d_in[13];
  const float* Ws = (const float*)d_in[14];
  const float* bs = (const float*)d_in[15];
  float* out = (float*)d_out;

  // workspace layout (12 MB used)
  char* ws = (char*)d_ws;
  unsigned short* Mt = (unsigned short*)(ws);               // 2 MB [NC][C][D]
  unsigned short* Vt = (unsigned short*)(ws + (2 << 20));   // 2 MB [NC][D][C]
  unsigned short* W1t = (unsigned short*)(ws + (4 << 20));  // 2 MB [NC][H][D]
  unsigned short* W2t = (unsigned short*)(ws + (6 << 20));  // 2 MB [NC][D][H]
  float* Ktmp = (float*)(ws + (8 << 20));                   // 4 MB [NC][C][D]

  kv_kernel<<<NC * 8, 256, 0, stream>>>(emb, Wk, Wv, Ktmp, Vt);
  m_kernel<<<NC * 8, 256, 0, stream>>>(Wq, Ktmp, Mt);
  tr_kernel<<<2 * NC * D * H / 256, 256, 0, stream>>>(W1, W2, W1t, W2t);
  fused_kernel<<<NC * 64, 256, 0, stream>>>(cat, Mt, Vt, W1t, W2t, b1, b2, g1,
                                            be1, g2, be2, Ws, bs, out);
}

// Round 3
// 163.634 us; speedup vs baseline: 1.9180x; 1.9180x over previous
//
#include <hip/hip_runtime.h>

// C2D_34419867910289 round 3 — same as r2 but fixes m_kernel's half-panel bug
// (was computing only d<64 of Mt; now acc[16] covers all 128 d per thread-group).
// r2 design: 80KB LDS (2 blocks/CU), quarter-panel double-buffered
// global_load_lds pipeline with counted vmcnt, XOR-swizzled (pre-swizzled in
// global) panels for conflict-free ds_read_b128, XCD-chunked block swizzle.

typedef __attribute__((ext_vector_type(4))) float f32x4;
typedef __attribute__((ext_vector_type(8))) short bf16x8;

#define DEVI static __device__ __forceinline__
#define SB __builtin_amdgcn_sched_barrier(0)
#define BARR __builtin_amdgcn_s_barrier()
#define MEMF asm volatile("" ::: "memory")

constexpr int NC = 32, D = 128, C = 256, H = 256;

DEVI unsigned short f2b(float f) {  // RN-even float -> bf16
  unsigned u = __builtin_bit_cast(unsigned, f);
  u += 0x7fffu + ((u >> 16) & 1u);
  return (unsigned short)(u >> 16);
}
DEVI float b2f(unsigned short h) {
  unsigned u = ((unsigned)h) << 16;
  return __builtin_bit_cast(float, u);
}
DEVI unsigned pk2(float a, float b) {
  return (unsigned)f2b(a) | ((unsigned)f2b(b) << 16);
}

template <int N> DEVI void vmwait() {
  asm volatile("s_waitcnt vmcnt(%0)" ::"n"(N) : "memory");
}
DEVI void lgkm0() { asm volatile("s_waitcnt lgkmcnt(0)" ::: "memory"); }

DEVI void gload16(const void* g, void* l) {
  __builtin_amdgcn_global_load_lds(
      (const __attribute__((address_space(1))) void*)g,
      (__attribute__((address_space(3))) void*)l, 16, 0, 0);
}

// Swizzle convention for all bf16 panels, keyed on panel row (8-row period):
//   byte = row*RB + ((slot ^ (row&7))<<4) + (elem&7)*2 ,  slot = col>>3
// RB = 256 for [256 rows][128 cols] panels (Mt, W1t)
// RB = 512 for [128 rows][256 cols] panels (Vt, W2t)

// ---------------- prep: K (fp32 tmp) and swizzled V^T ----------------
__global__ __launch_bounds__(256) void kv_kernel(
    const float* __restrict__ emb, const float* __restrict__ Wk,
    const float* __restrict__ Wv, float* __restrict__ Ktmp,
    unsigned short* __restrict__ VtP) {
  __shared__ float wk[D][D];
  __shared__ float wv[D][D];
  __shared__ float eb[32][D];
  const int j = blockIdx.x >> 3, ct = blockIdx.x & 7, tid = threadIdx.x;
  const float4* gk = (const float4*)(Wk + j * D * D);
  const float4* gv = (const float4*)(Wv + j * D * D);
  float4* lk = (float4*)&wk[0][0];
  float4* lv = (float4*)&wv[0][0];
  for (int i = tid; i < D * D / 4; i += 256) { lk[i] = gk[i]; lv[i] = gv[i]; }
  const float4* ge = (const float4*)(emb + (j * C + ct * 32) * D);
  float4* le = (float4*)&eb[0][0];
  for (int i = tid; i < 32 * D / 4; i += 256) le[i] = ge[i];
  __syncthreads();
  const int e = tid & 127, sel = tid >> 7;
  const float(*w)[D] = sel ? (const float(*)[D])wv : (const float(*)[D])wk;
  float acc[32];
#pragma unroll
  for (int r = 0; r < 32; ++r) acc[r] = 0.f;
  for (int d = 0; d < D; ++d) {
    float wde = w[d][e];
#pragma unroll
    for (int r = 0; r < 32; ++r) acc[r] = fmaf(eb[r][d], wde, acc[r]);
  }
  if (sel == 0) {
    for (int r = 0; r < 32; ++r) Ktmp[(j * C + ct * 32 + r) * D + e] = acc[r];
  } else {
    // VtP[e][c] = V[c][e], swizzled, rows of 512B
#pragma unroll
    for (int k = 0; k < 4; ++k) {
      uint4 pk = {pk2(acc[k * 8 + 0], acc[k * 8 + 1]),
                  pk2(acc[k * 8 + 2], acc[k * 8 + 3]),
                  pk2(acc[k * 8 + 4], acc[k * 8 + 5]),
                  pk2(acc[k * 8 + 6], acc[k * 8 + 7])};
      int slot = (ct << 2) + k;
      long byte = (long)j * 65536 + e * 512 + ((slot ^ (e & 7)) << 4);
      *(uint4*)((char*)VtP + byte) = pk;
    }
  }
}

// ---- prep: MtP[c][d] = (1/sqrt(D)) * sum_e Wq[d][e]K[c][e], swizzled ----
__global__ __launch_bounds__(256) void m_kernel(
    const float* __restrict__ Wq, const float* __restrict__ Ktmp,
    unsigned short* __restrict__ MtP) {
  __shared__ float wqT[128][132];  // wqT[e][d] = Wq[d][e]
  __shared__ float kt[32][129];
  const int j = blockIdx.x >> 3, ct = blockIdx.x & 7, tid = threadIdx.x;
  for (int i = tid; i < 128 * 32; i += 256) {
    int d = i >> 5, e4 = i & 31;
    float4 v = *(const float4*)(Wq + ((long)j * 128 + d) * 128 + e4 * 4);
    wqT[e4 * 4 + 0][d] = v.x; wqT[e4 * 4 + 1][d] = v.y;
    wqT[e4 * 4 + 2][d] = v.z; wqT[e4 * 4 + 3][d] = v.w;
  }
  for (int i = tid; i < 32 * 32; i += 256) {
    int r = i >> 5, c0 = (i & 31) * 4;
    float4 v = *(const float4*)(Ktmp + ((long)j * 256 + ct * 32 + r) * 128 + c0);
    kt[r][c0 + 0] = v.x; kt[r][c0 + 1] = v.y;
    kt[r][c0 + 2] = v.z; kt[r][c0 + 3] = v.w;
  }
  __syncthreads();
  const int cl = tid >> 3, s = tid & 7;  // c-local 0..31, d-group 0..7 (16 d each)
  float acc[16];
#pragma unroll
  for (int u = 0; u < 16; ++u) acc[u] = 0.f;
  for (int e = 0; e < 128; ++e) {
    float kk = kt[cl][e];
#pragma unroll
    for (int u = 0; u < 4; ++u) {
      float4 wv4 = *(const float4*)&wqT[e][s * 16 + u * 4];
      acc[u * 4 + 0] = fmaf(wv4.x, kk, acc[u * 4 + 0]);
      acc[u * 4 + 1] = fmaf(wv4.y, kk, acc[u * 4 + 1]);
      acc[u * 4 + 2] = fmaf(wv4.z, kk, acc[u * 4 + 2]);
      acc[u * 4 + 3] = fmaf(wv4.w, kk, acc[u * 4 + 3]);
    }
  }
  const float scale = 0.08838834764831845f;  // 1/sqrt(128)
  int c = ct * 32 + cl;
  uint4 pkA = {pk2(acc[0] * scale, acc[1] * scale),
               pk2(acc[2] * scale, acc[3] * scale),
               pk2(acc[4] * scale, acc[5] * scale),
               pk2(acc[6] * scale, acc[7] * scale)};
  uint4 pkB = {pk2(acc[8] * scale, acc[9] * scale),
               pk2(acc[10] * scale, acc[11] * scale),
               pk2(acc[12] * scale, acc[13] * scale),
               pk2(acc[14] * scale, acc[15] * scale)};
  long byteA = (long)j * 65536 + c * 256 + (((2 * s) ^ (c & 7)) << 4);
  long byteB = (long)j * 65536 + c * 256 + (((2 * s + 1) ^ (c & 7)) << 4);
  *(uint4*)((char*)MtP + byteA) = pkA;
  *(uint4*)((char*)MtP + byteB) = pkB;
}

// ---- prep: transposed + swizzled bf16 W1tP[h][d], W2tP[e][h] ----
__global__ __launch_bounds__(256) void tr_kernel(
    const float* __restrict__ W1, const float* __restrict__ W2,
    unsigned short* __restrict__ W1tP, unsigned short* __restrict__ W2tP) {
  __shared__ float t[32][33];
  const int b = blockIdx.x;
  const bool isW2 = b >= 1024;
  const int bb = isW2 ? b - 1024 : b;
  const int j = bb >> 5, tile = bb & 31;
  const int tid = threadIdx.x, rr = tid >> 3, c4 = tid & 7;
  if (!isW2) {
    const int dt = tile & 3, ht = tile >> 2;
    float4 v = *(const float4*)(W1 + ((long)j * 128 + dt * 32 + rr) * 256 + ht * 32 + c4 * 4);
    t[rr][c4 * 4 + 0] = v.x; t[rr][c4 * 4 + 1] = v.y;
    t[rr][c4 * 4 + 2] = v.z; t[rr][c4 * 4 + 3] = v.w;
    __syncthreads();
    int row = ht * 32 + rr, colb = dt * 32 + c4 * 4;
    uint2 pk = {pk2(t[c4 * 4 + 0][rr], t[c4 * 4 + 1][rr]),
                pk2(t[c4 * 4 + 2][rr], t[c4 * 4 + 3][rr])};
    long byte = (long)j * 65536 + row * 256 + (((colb >> 3) ^ (row & 7)) << 4) + (colb & 7) * 2;
    *(uint2*)((char*)W1tP + byte) = pk;
  } else {
    const int et = tile & 3, ht = tile >> 2;
    float4 v = *(const float4*)(W2 + ((long)j * 256 + ht * 32 + rr) * 128 + et * 32 + c4 * 4);
    t[rr][c4 * 4 + 0] = v.x; t[rr][c4 * 4 + 1] = v.y;
    t[rr][c4 * 4 + 2] = v.z; t[rr][c4 * 4 + 3] = v.w;
    __syncthreads();
    int row = et * 32 + rr, colb = ht * 32 + c4 * 4;
    uint2 pk = {pk2(t[c4 * 4 + 0][rr], t[c4 * 4 + 1][rr]),
                pk2(t[c4 * 4 + 2][rr], t[c4 * 4 + 3][rr])};
    long byte = (long)j * 65536 + row * 512 + (((colb >> 3) ^ (row & 7)) << 4) + (colb & 7) * 2;
    *(uint2*)((char*)W2tP + byte) = pk;
  }
}

// ---------------- fused main kernel ----------------
// LDS: xb 16K (x tile, reused for h1), al 32K (alpha, reused for relu(ff1)),
// wb 2x16K quarter-panel double buffer. Total 80KB -> 2 blocks/CU.
// 16 quarter-stages: 0-3 Mt, 4-7 Vt, 8-11 W1t, 12-15 W2t.
__global__ __launch_bounds__(256, 2) void fused_kernel(
    const float* __restrict__ x, const unsigned short* __restrict__ MtP,
    const unsigned short* __restrict__ VtP, const unsigned short* __restrict__ W1tP,
    const unsigned short* __restrict__ W2tP, const float* __restrict__ b1,
    const float* __restrict__ b2, const float* __restrict__ g1,
    const float* __restrict__ be1, const float* __restrict__ g2,
    const float* __restrict__ be2, const float* __restrict__ Ws,
    const float* __restrict__ bs, float* __restrict__ out) {
  __shared__ __align__(16) unsigned short xb[8192];
  __shared__ __align__(16) unsigned short al[16384];
  __shared__ __align__(16) unsigned short wb[2][8192];
  const int bid = blockIdx.x;
  const int wg = (bid & 7) * 256 + (bid >> 3);  // XCD-chunked: 4 j's per XCD
  const int j = wg >> 6, b0 = (wg & 63) * 64;
  const int tid = threadIdx.x, w = tid >> 6, l = tid & 63, lr = l & 15, lg = l >> 4;

  const unsigned short* pnl0 = MtP + (long)j * 32768;
  const unsigned short* pnl1 = VtP + (long)j * 32768;
  const unsigned short* pnl2 = W1tP + (long)j * 32768;
  const unsigned short* pnl3 = W2tP + (long)j * 32768;

  auto ISSUE = [&](int s2) {
    const unsigned short* base = (s2 < 4) ? pnl0 : (s2 < 8) ? pnl1 : (s2 < 12) ? pnl2 : pnl3;
    const char* gq = (const char*)(base + (s2 & 3) * 8192);
    char* lb = (char*)&wb[s2 & 1][0] + w * 4096;
    SB;
#pragma unroll
    for (int t = 0; t < 4; ++t)
      gload16(gq + (w * 4 + t) * 1024 + l * 16, lb + t * 1024);
    SB;
  };

  // ---- prologue: x loads, bs, first two stage issues, x -> LDS (bf16, swz)
  float4 xv[4][2];
#pragma unroll
  for (int it = 0; it < 4; ++it) {
    int r = (tid >> 4) + it * 16, s = tid & 15;
    const float4* p = (const float4*)(x + ((long)(b0 + r) * NC + j) * D + s * 8);
    xv[it][0] = p[0];
    xv[it][1] = p[1];
  }
  float bsj = bs[j];
  ISSUE(0);
  ISSUE(1);
#pragma unroll
  for (int it = 0; it < 4; ++it) {
    int r = (tid >> 4) + it * 16, s = tid & 15;
    uint4 pk = {pk2(xv[it][0].x, xv[it][0].y), pk2(xv[it][0].z, xv[it][0].w),
                pk2(xv[it][1].x, xv[it][1].y), pk2(xv[it][1].z, xv[it][1].w)};
    *(uint4*)((char*)xb + r * 256 + ((s ^ (r & 7)) << 4)) = pk;
  }
  lgkm0(); SB; BARR; MEMF; SB;

  int inner[4], inner2[8];
#pragma unroll
  for (int kc = 0; kc < 4; ++kc)
    inner[kc] = lr * 256 + (((kc * 4 + lg) ^ (lr & 7)) << 4);
#pragma unroll
  for (int kc = 0; kc < 8; ++kc)
    inner2[kc] = lr * 512 + (((kc * 4 + lg) ^ (lr & 7)) << 4);

  float g1v[8], be1v[8], b1v[16], b2v[8], g2v[8], be2v[8], wsv[8];
  float hv[8][4];

  // ---- GEMM1: scores = x @ Mt^T (stages 0..3) ----
  bf16x8 xa[4];
#pragma unroll
  for (int kc = 0; kc < 4; ++kc)
    xa[kc] = *(const bf16x8*)((const char*)xb + w * 4096 + inner[kc]);
  f32x4 sc[16];
#pragma unroll
  for (int t = 0; t < 16; ++t) sc[t] = (f32x4){0.f, 0.f, 0.f, 0.f};
#pragma unroll
  for (int q = 0; q < 4; ++q) {
    vmwait<4>(); SB; BARR; MEMF; SB;
    const char* wp = (const char*)wb[q & 1];
#pragma unroll
    for (int c4 = 0; c4 < 4; ++c4)
#pragma unroll
      for (int kc = 0; kc < 4; ++kc) {
        bf16x8 bf = *(const bf16x8*)(wp + c4 * 4096 + inner[kc]);
        sc[q * 4 + c4] =
            __builtin_amdgcn_mfma_f32_16x16x32_bf16(xa[kc], bf, sc[q * 4 + c4], 0, 0, 0);
      }
    if (q == 3) {
      // softmax over 256 cols; rows live across the 16 lanes of group lg
      float mx[4] = {-1e30f, -1e30f, -1e30f, -1e30f};
#pragma unroll
      for (int ct = 0; ct < 16; ++ct)
#pragma unroll
        for (int i = 0; i < 4; ++i) mx[i] = fmaxf(mx[i], sc[ct][i]);
#pragma unroll
      for (int m = 1; m < 16; m <<= 1)
#pragma unroll
        for (int i = 0; i < 4; ++i) mx[i] = fmaxf(mx[i], __shfl_xor(mx[i], m));
      float sm[4] = {0.f, 0.f, 0.f, 0.f};
#pragma unroll
      for (int ct = 0; ct < 16; ++ct)
#pragma unroll
        for (int i = 0; i < 4; ++i) {
          float e = __expf(sc[ct][i] - mx[i]);
          sc[ct][i] = e;
          sm[i] += e;
        }
#pragma unroll
      for (int m = 1; m < 16; m <<= 1)
#pragma unroll
        for (int i = 0; i < 4; ++i) sm[i] += __shfl_xor(sm[i], m);
      float inv[4];
#pragma unroll
      for (int i = 0; i < 4; ++i) inv[i] = 1.f / sm[i];
#pragma unroll
      for (int ct = 0; ct < 16; ++ct)
#pragma unroll
        for (int i = 0; i < 4; ++i) {
          int row = w * 16 + lg * 4 + i;
          int slot = ct * 2 + (lr >> 3);
          int byte = row * 512 + ((slot ^ (row & 7)) << 4) + (lr & 7) * 2;
          *(unsigned short*)((char*)al + byte) = f2b(sc[ct][i] * inv[i]);
        }
    }
    lgkm0(); SB; BARR; MEMF; SB;
    ISSUE(q + 2);
  }

  // ---- GEMM2: h = alpha @ V (stages 4..7) ----
  f32x4 ha[8];
#pragma unroll
  for (int t = 0; t < 8; ++t) ha[t] = (f32x4){0.f, 0.f, 0.f, 0.f};
  bf16x8 aa[8];
#pragma unroll
  for (int q = 0; q < 4; ++q) {
    if (q == 1) { vmwait<20>(); } else { vmwait<4>(); }
    SB; BARR; MEMF; SB;
    if (q == 0) {
#pragma unroll
      for (int kc = 0; kc < 8; ++kc)
        aa[kc] = *(const bf16x8*)((const char*)al + w * 8192 + inner2[kc]);
    }
    const char* wp = (const char*)wb[q & 1];
#pragma unroll
    for (int e2 = 0; e2 < 2; ++e2)
#pragma unroll
      for (int kc = 0; kc < 8; ++kc) {
        bf16x8 bf = *(const bf16x8*)(wp + e2 * 8192 + inner2[kc]);
        ha[q * 2 + e2] =
            __builtin_amdgcn_mfma_f32_16x16x32_bf16(aa[kc], bf, ha[q * 2 + e2], 0, 0, 0);
      }
    if (q == 3) {
      // residual + LN1; h1 -> xb (overwrites x, same-thread elements)
      float s1[4] = {0.f, 0.f, 0.f, 0.f}, s2s[4] = {0.f, 0.f, 0.f, 0.f};
#pragma unroll
      for (int et = 0; et < 8; ++et)
#pragma unroll
        for (int i = 0; i < 4; ++i) {
          int row = w * 16 + lg * 4 + i;
          int byte = row * 256 + (((et * 2 + (lr >> 3)) ^ (row & 7)) << 4) + (lr & 7) * 2;
          float v = ha[et][i] + b2f(*(const unsigned short*)((const char*)xb + byte));
          hv[et][i] = v;
          s1[i] += v;
          s2s[i] += v * v;
        }
#pragma unroll
      for (int m = 1; m < 16; m <<= 1)
#pragma unroll
        for (int i = 0; i < 4; ++i) {
          s1[i] += __shfl_xor(s1[i], m);
          s2s[i] += __shfl_xor(s2s[i], m);
        }
#pragma unroll
      for (int i = 0; i < 4; ++i) {
        float mu = s1[i] * (1.f / 128.f);
        float var = s2s[i] * (1.f / 128.f) - mu * mu;
        float rs = rsqrtf(var + 1e-5f);
#pragma unroll
        for (int et = 0; et < 8; ++et) {
          int row = w * 16 + lg * 4 + i;
          int byte = row * 256 + (((et * 2 + (lr >> 3)) ^ (row & 7)) << 4) + (lr & 7) * 2;
          float hn = (hv[et][i] - mu) * rs * g1v[et] + be1v[et];
          hv[et][i] = hn;
          *(unsigned short*)((char*)xb + byte) = f2b(hn);
        }
      }
    }
    lgkm0(); SB; BARR; MEMF; SB;
    if (q == 0) {
      SB;
#pragma unroll
      for (int et = 0; et < 8; ++et) {
        g1v[et] = g1[et * 16 + lr];
        be1v[et] = be1[et * 16 + lr];
      }
      SB;
    }
    ISSUE(6 + q);
  }

  // ---- GEMM3: ff1 = relu(h1 @ W1 + b1) (stages 8..11) ----
  bf16x8 xa2[4];
  f32x4 fa[16];
#pragma unroll
  for (int t = 0; t < 16; ++t) fa[t] = (f32x4){0.f, 0.f, 0.f, 0.f};
#pragma unroll
  for (int q = 0; q < 4; ++q) {
    if (q == 1) { vmwait<20>(); } else { vmwait<4>(); }
    SB; BARR; MEMF; SB;
    if (q == 0) {
#pragma unroll
      for (int kc = 0; kc < 4; ++kc)
        xa2[kc] = *(const bf16x8*)((const char*)xb + w * 4096 + inner[kc]);
    }
    const char* wp = (const char*)wb[q & 1];
#pragma unroll
    for (int c4 = 0; c4 < 4; ++c4)
#pragma unroll
      for (int kc = 0; kc < 4; ++kc) {
        bf16x8 bf = *(const bf16x8*)(wp + c4 * 4096 + inner[kc]);
        fa[q * 4 + c4] =
            __builtin_amdgcn_mfma_f32_16x16x32_bf16(xa2[kc], bf, fa[q * 4 + c4], 0, 0, 0);
      }
    if (q == 3) {
      // relu + b1 -> al
#pragma unroll
      for (int ht = 0; ht < 16; ++ht)
#pragma unroll
        for (int i = 0; i < 4; ++i) {
          int row = w * 16 + lg * 4 + i;
          int slot = ht * 2 + (lr >> 3);
          int byte = row * 512 + ((slot ^ (row & 7)) << 4) + (lr & 7) * 2;
          float v = fmaxf(fa[ht][i] + b1v[ht], 0.f);
          *(unsigned short*)((char*)al + byte) = f2b(v);
        }
    }
    lgkm0(); SB; BARR; MEMF; SB;
    if (q == 0) {
      SB;
#pragma unroll
      for (int ht = 0; ht < 16; ++ht) b1v[ht] = b1[j * 256 + ht * 16 + lr];
      SB;
    }
    ISSUE(10 + q);
  }

  // ---- GEMM4: ff2 + residual + LN2 + sigmoid readout (stages 12..15) ----
  f32x4 oa[8];
#pragma unroll
  for (int t = 0; t < 8; ++t) oa[t] = (f32x4){0.f, 0.f, 0.f, 0.f};
  bf16x8 aa2[8];
#pragma unroll
  for (int q = 0; q < 4; ++q) {
    if (q == 1) { vmwait<36>(); } else if (q == 3) { vmwait<0>(); } else { vmwait<4>(); }
    SB; BARR; MEMF; SB;
    if (q == 0) {
#pragma unroll
      for (int kc = 0; kc < 8; ++kc)
        aa2[kc] = *(const bf16x8*)((const char*)al + w * 8192 + inner2[kc]);
    }
    const char* wp = (const char*)wb[q & 1];
#pragma unroll
    for (int e2 = 0; e2 < 2; ++e2)
#pragma unroll
      for (int kc = 0; kc < 8; ++kc) {
        bf16x8 bf = *(const bf16x8*)(wp + e2 * 8192 + inner2[kc]);
        oa[q * 2 + e2] =
            __builtin_amdgcn_mfma_f32_16x16x32_bf16(aa2[kc], bf, oa[q * 2 + e2], 0, 0, 0);
      }
    if (q < 3) {
      lgkm0(); SB; BARR; MEMF; SB;
      if (q == 0) {
        SB;
#pragma unroll
        for (int et = 0; et < 8; ++et) {
          b2v[et] = b2[j * 128 + et * 16 + lr];
          g2v[et] = g2[et * 16 + lr];
          be2v[et] = be2[et * 16 + lr];
          wsv[et] = Ws[j * 128 + et * 16 + lr];
        }
        SB;
      }
      if (q < 2) ISSUE(14 + q);
    }
  }
  // final epilogue
  {
    float t1[4] = {0.f, 0.f, 0.f, 0.f}, t2[4] = {0.f, 0.f, 0.f, 0.f};
#pragma unroll
    for (int et = 0; et < 8; ++et)
#pragma unroll
      for (int i = 0; i < 4; ++i) {
        float v = oa[et][i] + b2v[et] + hv[et][i];
        oa[et][i] = v;
        t1[i] += v;
        t2[i] += v * v;
      }
#pragma unroll
    for (int m = 1; m < 16; m <<= 1)
#pragma unroll
      for (int i = 0; i < 4; ++i) {
        t1[i] += __shfl_xor(t1[i], m);
        t2[i] += __shfl_xor(t2[i], m);
      }
    float lp[4] = {0.f, 0.f, 0.f, 0.f};
#pragma unroll
    for (int i = 0; i < 4; ++i) {
      float mu2 = t1[i] * (1.f / 128.f);
      float var = t2[i] * (1.f / 128.f) - mu2 * mu2;
      float rs2 = rsqrtf(var + 1e-5f);
#pragma unroll
      for (int et = 0; et < 8; ++et) {
        float h2 = (oa[et][i] - mu2) * rs2 * g2v[et] + be2v[et];
        lp[i] = fmaf(h2, wsv[et], lp[i]);
      }
    }
#pragma unroll
    for (int m = 1; m < 16; m <<= 1)
#pragma unroll
      for (int i = 0; i < 4; ++i) lp[i] += __shfl_xor(lp[i], m);
    if (lr == 0) {
#pragma unroll
      for (int i = 0; i < 4; ++i) {
        float sg = 1.f / (1.f + __expf(-(lp[i] + bsj)));
        out[(long)(b0 + w * 16 + lg * 4 + i) * NC + j] = sg;
      }
    }
  }
}

extern "C" void kernel_launch(void* const* d_in, const int* in_sizes, int n_in,
                              void* d_out, int out_size, void* d_ws,
                              size_t ws_size, hipStream_t stream) {
  (void)in_sizes; (void)n_in; (void)out_size; (void)ws_size;
  const float* cat = (const float*)d_in[1];
  const float* emb = (const float*)d_in[2];
  const float* Wq = (const float*)d_in[3];
  const float* Wk = (const float*)d_in[4];
  const float* Wv = (const float*)d_in[5];
  const float* g1 = (const float*)d_in[6];
  const float* be1 = (const float*)d_in[7];
  const float* W1 = (const float*)d_in[8];
  const float* b1 = (const float*)d_in[9];
  const float* W2 = (const float*)d_in[10];
  const float* b2 = (const float*)d_in[11];
  const float* g2 = (const float*)d_in[12];
  const float* be2 = (const float*)d_in[13];
  const float* Ws = (const float*)d_in[14];
  const float* bs = (const float*)d_in[15];
  float* out = (float*)d_out;

  // workspace: 12 MB
  char* ws = (char*)d_ws;
  unsigned short* MtP = (unsigned short*)(ws);              // 2 MB swz [NC][256][128]
  unsigned short* VtP = (unsigned short*)(ws + (2 << 20));  // 2 MB swz [NC][128][256]
  unsigned short* W1tP = (unsigned short*)(ws + (4 << 20)); // 2 MB swz [NC][256][128]
  unsigned short* W2tP = (unsigned short*)(ws + (6 << 20)); // 2 MB swz [NC][128][256]
  float* Ktmp = (float*)(ws + (8 << 20));                   // 4 MB [NC][256][128]

  kv_kernel<<<NC * 8, 256, 0, stream>>>(emb, Wk, Wv, Ktmp, VtP);
  m_kernel<<<NC * 8, 256, 0, stream>>>(Wq, Ktmp, MtP);
  tr_kernel<<<2048, 256, 0, stream>>>(W1, W2, W1tP, W2tP);
  fused_kernel<<<2048, 256, 0, stream>>>(cat, MtP, VtP, W1tP, W2tP, b1, b2, g1,
                                         be1, g2, be2, Ws, bs, out);
}

// Round 5
// 148.207 us; speedup vs baseline: 2.1177x; 1.1041x over previous
//
#include <hip/hip_runtime.h>

// C2D_34419867910289 round 5 — identical to round 4 (bench infra failed; resubmit).
// Transposed-chain fused kernel: all GEMMs as C^T = mfma(A=weight-panel,
// B=activation). Panel LDS reads byte-identical to r3; thread ownership is
// (one batch col b, 4-contig feature rows) -> epilogue LDS ops are b64/b128
// (was scalar u16 = the 9.17M conflict cycles). sv param buffer in LDS; x/h1
// folded into al bytes (disjoint lifetimes); LN1 residual snapshot in regs;
// setprio around MFMA clusters. LDS 80->68KB (still 2 blocks/CU).

typedef __attribute__((ext_vector_type(4))) float f32x4;
typedef __attribute__((ext_vector_type(8))) short bf16x8;

#define DEVI static __device__ __forceinline__
#define SB __builtin_amdgcn_sched_barrier(0)
#define BARR __builtin_amdgcn_s_barrier()
#define MEMF asm volatile("" ::: "memory")

constexpr int NC = 32, D = 128, C = 256, H = 256;

DEVI unsigned short f2b(float f) {  // RN-even float -> bf16
  unsigned u = __builtin_bit_cast(unsigned, f);
  u += 0x7fffu + ((u >> 16) & 1u);
  return (unsigned short)(u >> 16);
}
DEVI float b2f(unsigned short h) {
  unsigned u = ((unsigned)h) << 16;
  return __builtin_bit_cast(float, u);
}
DEVI unsigned pk2(float a, float b) {
  return (unsigned)f2b(a) | ((unsigned)f2b(b) << 16);
}

template <int N> DEVI void vmwait() {
  asm volatile("s_waitcnt vmcnt(%0)" ::"n"(N) : "memory");
}
DEVI void lgkm0() { asm volatile("s_waitcnt lgkmcnt(0)" ::: "memory"); }

DEVI void gload16(const void* g, void* l) {
  __builtin_amdgcn_global_load_lds(
      (const __attribute__((address_space(1))) void*)g,
      (__attribute__((address_space(3))) void*)l, 16, 0, 0);
}

// Swizzle for all bf16 panels/tiles, keyed on row (8-row period):
//   byte = row*RB + ((slot ^ (row&7))<<4) + (elem&7)*2 ,  slot = col>>3

// ---------------- prep: K (fp32 tmp) and swizzled V^T ----------------
__global__ __launch_bounds__(256) void kv_kernel(
    const float* __restrict__ emb, const float* __restrict__ Wk,
    const float* __restrict__ Wv, float* __restrict__ Ktmp,
    unsigned short* __restrict__ VtP) {
  __shared__ float wk[D][D];
  __shared__ float wv[D][D];
  __shared__ float eb[32][D];
  const int j = blockIdx.x >> 3, ct = blockIdx.x & 7, tid = threadIdx.x;
  const float4* gk = (const float4*)(Wk + j * D * D);
  const float4* gv = (const float4*)(Wv + j * D * D);
  float4* lk = (float4*)&wk[0][0];
  float4* lv = (float4*)&wv[0][0];
  for (int i = tid; i < D * D / 4; i += 256) { lk[i] = gk[i]; lv[i] = gv[i]; }
  const float4* ge = (const float4*)(emb + (j * C + ct * 32) * D);
  float4* le = (float4*)&eb[0][0];
  for (int i = tid; i < 32 * D / 4; i += 256) le[i] = ge[i];
  __syncthreads();
  const int e = tid & 127, sel = tid >> 7;
  const float(*w)[D] = sel ? (const float(*)[D])wv : (const float(*)[D])wk;
  float acc[32];
#pragma unroll
  for (int r = 0; r < 32; ++r) acc[r] = 0.f;
  for (int d = 0; d < D; ++d) {
    float wde = w[d][e];
#pragma unroll
    for (int r = 0; r < 32; ++r) acc[r] = fmaf(eb[r][d], wde, acc[r]);
  }
  if (sel == 0) {
    for (int r = 0; r < 32; ++r) Ktmp[(j * C + ct * 32 + r) * D + e] = acc[r];
  } else {
#pragma unroll
    for (int k = 0; k < 4; ++k) {
      uint4 pk = {pk2(acc[k * 8 + 0], acc[k * 8 + 1]),
                  pk2(acc[k * 8 + 2], acc[k * 8 + 3]),
                  pk2(acc[k * 8 + 4], acc[k * 8 + 5]),
                  pk2(acc[k * 8 + 6], acc[k * 8 + 7])};
      int slot = (ct << 2) + k;
      long byte = (long)j * 65536 + e * 512 + ((slot ^ (e & 7)) << 4);
      *(uint4*)((char*)VtP + byte) = pk;
    }
  }
}

// ---- prep: MtP[c][d] = (1/sqrt(D)) * sum_e Wq[d][e]K[c][e], swizzled ----
__global__ __launch_bounds__(256) void m_kernel(
    const float* __restrict__ Wq, const float* __restrict__ Ktmp,
    unsigned short* __restrict__ MtP) {
  __shared__ float wqT[128][132];  // wqT[e][d] = Wq[d][e]
  __shared__ float kt[32][129];
  const int j = blockIdx.x >> 3, ct = blockIdx.x & 7, tid = threadIdx.x;
  for (int i = tid; i < 128 * 32; i += 256) {
    int d = i >> 5, e4 = i & 31;
    float4 v = *(const float4*)(Wq + ((long)j * 128 + d) * 128 + e4 * 4);
    wqT[e4 * 4 + 0][d] = v.x; wqT[e4 * 4 + 1][d] = v.y;
    wqT[e4 * 4 + 2][d] = v.z; wqT[e4 * 4 + 3][d] = v.w;
  }
  for (int i = tid; i < 32 * 32; i += 256) {
    int r = i >> 5, c0 = (i & 31) * 4;
    float4 v = *(const float4*)(Ktmp + ((long)j * 256 + ct * 32 + r) * 128 + c0);
    kt[r][c0 + 0] = v.x; kt[r][c0 + 1] = v.y;
    kt[r][c0 + 2] = v.z; kt[r][c0 + 3] = v.w;
  }
  __syncthreads();
  const int cl = tid >> 3, s = tid & 7;  // c-local 0..31, d-group 0..7 (16 d)
  float acc[16];
#pragma unroll
  for (int u = 0; u < 16; ++u) acc[u] = 0.f;
  for (int e = 0; e < 128; ++e) {
    float kk = kt[cl][e];
#pragma unroll
    for (int u = 0; u < 4; ++u) {
      float4 wv4 = *(const float4*)&wqT[e][s * 16 + u * 4];
      acc[u * 4 + 0] = fmaf(wv4.x, kk, acc[u * 4 + 0]);
      acc[u * 4 + 1] = fmaf(wv4.y, kk, acc[u * 4 + 1]);
      acc[u * 4 + 2] = fmaf(wv4.z, kk, acc[u * 4 + 2]);
      acc[u * 4 + 3] = fmaf(wv4.w, kk, acc[u * 4 + 3]);
    }
  }
  const float scale = 0.08838834764831845f;  // 1/sqrt(128)
  int c = ct * 32 + cl;
  uint4 pkA = {pk2(acc[0] * scale, acc[1] * scale),
               pk2(acc[2] * scale, acc[3] * scale),
               pk2(acc[4] * scale, acc[5] * scale),
               pk2(acc[6] * scale, acc[7] * scale)};
  uint4 pkB = {pk2(acc[8] * scale, acc[9] * scale),
               pk2(acc[10] * scale, acc[11] * scale),
               pk2(acc[12] * scale, acc[13] * scale),
               pk2(acc[14] * scale, acc[15] * scale)};
  long byteA = (long)j * 65536 + c * 256 + (((2 * s) ^ (c & 7)) << 4);
  long byteB = (long)j * 65536 + c * 256 + (((2 * s + 1) ^ (c & 7)) << 4);
  *(uint4*)((char*)MtP + byteA) = pkA;
  *(uint4*)((char*)MtP + byteB) = pkB;
}

// ---- prep: transposed + swizzled bf16 W1tP[h][d], W2tP[e][h] ----
__global__ __launch_bounds__(256) void tr_kernel(
    const float* __restrict__ W1, const float* __restrict__ W2,
    unsigned short* __restrict__ W1tP, unsigned short* __restrict__ W2tP) {
  __shared__ float t[32][33];
  const int b = blockIdx.x;
  const bool isW2 = b >= 1024;
  const int bb = isW2 ? b - 1024 : b;
  const int j = bb >> 5, tile = bb & 31;
  const int tid = threadIdx.x, rr = tid >> 3, c4 = tid & 7;
  if (!isW2) {
    const int dt = tile & 3, ht = tile >> 2;
    float4 v = *(const float4*)(W1 + ((long)j * 128 + dt * 32 + rr) * 256 + ht * 32 + c4 * 4);
    t[rr][c4 * 4 + 0] = v.x; t[rr][c4 * 4 + 1] = v.y;
    t[rr][c4 * 4 + 2] = v.z; t[rr][c4 * 4 + 3] = v.w;
    __syncthreads();
    int row = ht * 32 + rr, colb = dt * 32 + c4 * 4;
    uint2 pk = {pk2(t[c4 * 4 + 0][rr], t[c4 * 4 + 1][rr]),
                pk2(t[c4 * 4 + 2][rr], t[c4 * 4 + 3][rr])};
    long byte = (long)j * 65536 + row * 256 + (((colb >> 3) ^ (row & 7)) << 4) + (colb & 7) * 2;
    *(uint2*)((char*)W1tP + byte) = pk;
  } else {
    const int et = tile & 3, ht = tile >> 2;
    float4 v = *(const float4*)(W2 + ((long)j * 256 + ht * 32 + rr) * 128 + et * 32 + c4 * 4);
    t[rr][c4 * 4 + 0] = v.x; t[rr][c4 * 4 + 1] = v.y;
    t[rr][c4 * 4 + 2] = v.z; t[rr][c4 * 4 + 3] = v.w;
    __syncthreads();
    int row = et * 32 + rr, colb = ht * 32 + c4 * 4;
    uint2 pk = {pk2(t[c4 * 4 + 0][rr], t[c4 * 4 + 1][rr]),
                pk2(t[c4 * 4 + 2][rr], t[c4 * 4 + 3][rr])};
    long byte = (long)j * 65536 + row * 512 + (((colb >> 3) ^ (row & 7)) << 4) + (colb & 7) * 2;
    *(uint2*)((char*)W2tP + byte) = pk;
  }
}

// ---------------- fused main kernel (transposed chain) ----------------
// LDS: al 32KB (x-tile/h1 share its bytes in disjoint phases; alpha/ff full),
// wb 2x16K quarter-panel double buffer, sv 4KB params. Total 68KB.
// Thread owns batch col b = w*16+lr; feature rows t*16 + lg*4 + i.
__global__ __launch_bounds__(256, 2) void fused_kernel(
    const float* __restrict__ x, const unsigned short* __restrict__ MtP,
    const unsigned short* __restrict__ VtP, const unsigned short* __restrict__ W1tP,
    const unsigned short* __restrict__ W2tP, const float* __restrict__ b1,
    const float* __restrict__ b2, const float* __restrict__ g1,
    const float* __restrict__ be1, const float* __restrict__ g2,
    const float* __restrict__ be2, const float* __restrict__ Ws,
    const float* __restrict__ bs, float* __restrict__ out) {
  __shared__ __align__(16) unsigned short al[16384];  // 32KB
  __shared__ __align__(16) unsigned short wb[2][8192];
  __shared__ __align__(16) float sv[1024];
  const int bid = blockIdx.x;
  const int wg = (bid & 7) * 256 + (bid >> 3);  // XCD-chunked
  const int j = wg >> 6, b0 = (wg & 63) * 64;
  const int tid = threadIdx.x, w = tid >> 6, l = tid & 63, lr = l & 15, lg = l >> 4;

  const unsigned short* pnl0 = MtP + (long)j * 32768;
  const unsigned short* pnl1 = VtP + (long)j * 32768;
  const unsigned short* pnl2 = W1tP + (long)j * 32768;
  const unsigned short* pnl3 = W2tP + (long)j * 32768;

  auto ISSUE = [&](int s2) {
    const unsigned short* base = (s2 < 4) ? pnl0 : (s2 < 8) ? pnl1 : (s2 < 12) ? pnl2 : pnl3;
    const char* gq = (const char*)(base + (s2 & 3) * 8192);
    char* lb = (char*)&wb[s2 & 1][0] + w * 4096;
    SB;
#pragma unroll
    for (int t = 0; t < 4; ++t)
      gload16(gq + (w * 4 + t) * 1024 + l * 16, lb + t * 1024);
    SB;
  };

  // ---- prologue: x tile -> al[0:16KB] ([64 b][128 d], 256B rows, swizzled),
  // sv params, first two stage issues.
  float4 xv[4][2];
#pragma unroll
  for (int it = 0; it < 4; ++it) {
    int r = (tid >> 4) + it * 16, s = tid & 15;
    const float4* p = (const float4*)(x + ((long)(b0 + r) * NC + j) * D + s * 8);
    xv[it][0] = p[0];
    xv[it][1] = p[1];
  }
  float bsj = bs[j];
  ISSUE(0);
  ISSUE(1);
  for (int i = tid; i < 1024; i += 256) {
    float v;
    if (i < 256) v = b1[j * H + i];
    else if (i < 384) v = b2[j * D + i - 256];
    else if (i < 512) v = g1[i - 384];
    else if (i < 640) v = be1[i - 512];
    else if (i < 768) v = g2[i - 640];
    else if (i < 896) v = be2[i - 768];
    else v = Ws[j * D + i - 896];
    sv[i] = v;
  }
#pragma unroll
  for (int it = 0; it < 4; ++it) {
    int r = (tid >> 4) + it * 16, s = tid & 15;
    uint4 pk = {pk2(xv[it][0].x, xv[it][0].y), pk2(xv[it][0].z, xv[it][0].w),
                pk2(xv[it][1].x, xv[it][1].y), pk2(xv[it][1].z, xv[it][1].w)};
    *(uint4*)((char*)al + r * 256 + ((s ^ (r & 7)) << 4)) = pk;
  }
  lgkm0(); SB; BARR; MEMF; SB;

  const int bloc = w * 16 + lr;
  int inner[4], inner2[8], res[8];
#pragma unroll
  for (int kc = 0; kc < 4; ++kc)
    inner[kc] = lr * 256 + (((kc * 4 + lg) ^ (lr & 7)) << 4);
#pragma unroll
  for (int kc = 0; kc < 8; ++kc)
    inner2[kc] = lr * 512 + (((kc * 4 + lg) ^ (lr & 7)) << 4);
#pragma unroll
  for (int et = 0; et < 8; ++et)
    res[et] = bloc * 256 + (((et * 2 + (lg >> 1)) ^ (lr & 7)) << 4) + (lg & 1) * 8;

  // x fragments (B-operand) + residual snapshot (before alpha overwrites)
  bf16x8 xa[4];
#pragma unroll
  for (int kc = 0; kc < 4; ++kc)
    xa[kc] = *(const bf16x8*)((const char*)al + w * 4096 + inner[kc]);
  uint2 xres[8];
#pragma unroll
  for (int et = 0; et < 8; ++et)
    xres[et] = *(const uint2*)((const char*)al + res[et]);

  float hv[8][4];

  // ---- GEMM1: S^T[c,b] = Mt @ x^T  (stages 0..3) ----
  f32x4 sc[16];
#pragma unroll
  for (int t = 0; t < 16; ++t) sc[t] = (f32x4){0.f, 0.f, 0.f, 0.f};
#pragma unroll
  for (int q = 0; q < 4; ++q) {
    vmwait<4>(); SB; BARR; MEMF; SB;
    const char* wp = (const char*)wb[q & 1];
    __builtin_amdgcn_s_setprio(1);
#pragma unroll
    for (int c4 = 0; c4 < 4; ++c4)
#pragma unroll
      for (int kc = 0; kc < 4; ++kc) {
        bf16x8 bf = *(const bf16x8*)(wp + c4 * 4096 + inner[kc]);
        sc[q * 4 + c4] =
            __builtin_amdgcn_mfma_f32_16x16x32_bf16(bf, xa[kc], sc[q * 4 + c4], 0, 0, 0);
      }
    __builtin_amdgcn_s_setprio(0);
    if (q == 3) {
      // softmax over c (in-thread 64 values + lg-reduction), alpha -> al[b][c]
      float mx = -1e30f;
#pragma unroll
      for (int ct = 0; ct < 16; ++ct)
#pragma unroll
        for (int i = 0; i < 4; ++i) mx = fmaxf(mx, sc[ct][i]);
      mx = fmaxf(mx, __shfl_xor(mx, 16));
      mx = fmaxf(mx, __shfl_xor(mx, 32));
      float sm = 0.f;
#pragma unroll
      for (int ct = 0; ct < 16; ++ct)
#pragma unroll
        for (int i = 0; i < 4; ++i) {
          float e = __expf(sc[ct][i] - mx);
          sc[ct][i] = e;
          sm += e;
        }
      sm += __shfl_xor(sm, 16);
      sm += __shfl_xor(sm, 32);
      float inv = 1.f / sm;
#pragma unroll
      for (int ct = 0; ct < 16; ++ct) {
        uint2 pk = {pk2(sc[ct][0] * inv, sc[ct][1] * inv),
                    pk2(sc[ct][2] * inv, sc[ct][3] * inv)};
        int byte = bloc * 512 + (((2 * ct + (lg >> 1)) ^ (lr & 7)) << 4) + (lg & 1) * 8;
        *(uint2*)((char*)al + byte) = pk;
      }
    }
    lgkm0(); SB; BARR; MEMF; SB;
    ISSUE(q + 2);
  }

  // ---- GEMM2: h^T[e,b] = V^T @ alpha^T (stages 4..7) ----
  f32x4 ha[8];
#pragma unroll
  for (int t = 0; t < 8; ++t) ha[t] = (f32x4){0.f, 0.f, 0.f, 0.f};
  bf16x8 aa[8];
#pragma unroll
  for (int q = 0; q < 4; ++q) {
    if (q == 1) { vmwait<20>(); } else { vmwait<4>(); }
    SB; BARR; MEMF; SB;
    if (q == 0) {
#pragma unroll
      for (int kc = 0; kc < 8; ++kc)
        aa[kc] = *(const bf16x8*)((const char*)al + w * 8192 + inner2[kc]);
    }
    const char* wp = (const char*)wb[q & 1];
    __builtin_amdgcn_s_setprio(1);
#pragma unroll
    for (int e2 = 0; e2 < 2; ++e2)
#pragma unroll
      for (int kc = 0; kc < 8; ++kc) {
        bf16x8 bf = *(const bf16x8*)(wp + e2 * 8192 + inner2[kc]);
        ha[q * 2 + e2] =
            __builtin_amdgcn_mfma_f32_16x16x32_bf16(bf, aa[kc], ha[q * 2 + e2], 0, 0, 0);
      }
    __builtin_amdgcn_s_setprio(0);
    if (q == 3) {
      // residual(from regs) + LN1; h1 -> al[0:16KB] ([b][d] 256B rows)
      float s1 = 0.f, s2s = 0.f;
#pragma unroll
      for (int et = 0; et < 8; ++et) {
        uint2 xr = xres[et];
        float v0 = ha[et][0] + b2f((unsigned short)(xr.x & 0xffff));
        float v1 = ha[et][1] + b2f((unsigned short)(xr.x >> 16));
        float v2 = ha[et][2] + b2f((unsigned short)(xr.y & 0xffff));
        float v3 = ha[et][3] + b2f((unsigned short)(xr.y >> 16));
        hv[et][0] = v0; hv[et][1] = v1; hv[et][2] = v2; hv[et][3] = v3;
        s1 += (v0 + v1) + (v2 + v3);
        s2s += (v0 * v0 + v1 * v1) + (v2 * v2 + v3 * v3);
      }
      s1 += __shfl_xor(s1, 16); s2s += __shfl_xor(s2s, 16);
      s1 += __shfl_xor(s1, 32); s2s += __shfl_xor(s2s, 32);
      float mu = s1 * (1.f / 128.f);
      float var = s2s * (1.f / 128.f) - mu * mu;
      float rs = rsqrtf(var + 1e-5f);
#pragma unroll
      for (int et = 0; et < 8; ++et) {
        f32x4 gg = *(const f32x4*)&sv[384 + et * 16 + lg * 4];
        f32x4 bb = *(const f32x4*)&sv[512 + et * 16 + lg * 4];
        float h0 = (hv[et][0] - mu) * rs * gg[0] + bb[0];
        float h1n = (hv[et][1] - mu) * rs * gg[1] + bb[1];
        float h2 = (hv[et][2] - mu) * rs * gg[2] + bb[2];
        float h3 = (hv[et][3] - mu) * rs * gg[3] + bb[3];
        hv[et][0] = h0; hv[et][1] = h1n; hv[et][2] = h2; hv[et][3] = h3;
        uint2 pk = {pk2(h0, h1n), pk2(h2, h3)};
        *(uint2*)((char*)al + res[et]) = pk;
      }
    }
    lgkm0(); SB; BARR; MEMF; SB;
    ISSUE(6 + q);
  }

  // ---- GEMM3: ff^T[h,b] = W1^T @ h1^T (stages 8..11) ----
  bf16x8 xa2[4];
  f32x4 fa[16];
#pragma unroll
  for (int t = 0; t < 16; ++t) fa[t] = (f32x4){0.f, 0.f, 0.f, 0.f};
#pragma unroll
  for (int q = 0; q < 4; ++q) {
    if (q == 1) { vmwait<20>(); } else { vmwait<4>(); }
    SB; BARR; MEMF; SB;
    if (q == 0) {
#pragma unroll
      for (int kc = 0; kc < 4; ++kc)
        xa2[kc] = *(const bf16x8*)((const char*)al + w * 4096 + inner[kc]);
    }
    const char* wp = (const char*)wb[q & 1];
    __builtin_amdgcn_s_setprio(1);
#pragma unroll
    for (int c4 = 0; c4 < 4; ++c4)
#pragma unroll
      for (int kc = 0; kc < 4; ++kc) {
        bf16x8 bf = *(const bf16x8*)(wp + c4 * 4096 + inner[kc]);
        fa[q * 4 + c4] =
            __builtin_amdgcn_mfma_f32_16x16x32_bf16(bf, xa2[kc], fa[q * 4 + c4], 0, 0, 0);
      }
    __builtin_amdgcn_s_setprio(0);
    if (q == 3) {
      // relu(ff + b1) -> al[b][h]
#pragma unroll
      for (int ht = 0; ht < 16; ++ht) {
        f32x4 bb = *(const f32x4*)&sv[ht * 16 + lg * 4];
        float v0 = fmaxf(fa[ht][0] + bb[0], 0.f);
        float v1 = fmaxf(fa[ht][1] + bb[1], 0.f);
        float v2 = fmaxf(fa[ht][2] + bb[2], 0.f);
        float v3 = fmaxf(fa[ht][3] + bb[3], 0.f);
        uint2 pk = {pk2(v0, v1), pk2(v2, v3)};
        int byte = bloc * 512 + (((2 * ht + (lg >> 1)) ^ (lr & 7)) << 4) + (lg & 1) * 8;
        *(uint2*)((char*)al + byte) = pk;
      }
    }
    lgkm0(); SB; BARR; MEMF; SB;
    ISSUE(10 + q);
  }

  // ---- GEMM4: o^T[e,b] = W2^T @ ff^T + LN2 + sigmoid (stages 12..15) ----
  f32x4 oa[8];
#pragma unroll
  for (int t = 0; t < 8; ++t) oa[t] = (f32x4){0.f, 0.f, 0.f, 0.f};
  bf16x8 aa2[8];
#pragma unroll
  for (int q = 0; q < 4; ++q) {
    if (q == 1) { vmwait<36>(); } else if (q == 3) { vmwait<0>(); } else { vmwait<4>(); }
    SB; BARR; MEMF; SB;
    if (q == 0) {
#pragma unroll
      for (int kc = 0; kc < 8; ++kc)
        aa2[kc] = *(const bf16x8*)((const char*)al + w * 8192 + inner2[kc]);
    }
    const char* wp = (const char*)wb[q & 1];
    __builtin_amdgcn_s_setprio(1);
#pragma unroll
    for (int e2 = 0; e2 < 2; ++e2)
#pragma unroll
      for (int kc = 0; kc < 8; ++kc) {
        bf16x8 bf = *(const bf16x8*)(wp + e2 * 8192 + inner2[kc]);
        oa[q * 2 + e2] =
            __builtin_amdgcn_mfma_f32_16x16x32_bf16(bf, aa2[kc], oa[q * 2 + e2], 0, 0, 0);
      }
    __builtin_amdgcn_s_setprio(0);
    if (q < 3) {
      lgkm0(); SB; BARR; MEMF; SB;
      if (q < 2) ISSUE(14 + q);
    }
  }
  // final epilogue: +b2 +h1, LN2, dot Ws, sigmoid
  {
    float t1 = 0.f, t2 = 0.f;
#pragma unroll
    for (int et = 0; et < 8; ++et) {
      f32x4 bb = *(const f32x4*)&sv[256 + et * 16 + lg * 4];
#pragma unroll
      for (int i = 0; i < 4; ++i) {
        float v = oa[et][i] + bb[i] + hv[et][i];
        oa[et][i] = v;
        t1 += v;
        t2 += v * v;
      }
    }
    t1 += __shfl_xor(t1, 16); t2 += __shfl_xor(t2, 16);
    t1 += __shfl_xor(t1, 32); t2 += __shfl_xor(t2, 32);
    float mu2 = t1 * (1.f / 128.f);
    float var = t2 * (1.f / 128.f) - mu2 * mu2;
    float rs2 = rsqrtf(var + 1e-5f);
    float lp = 0.f;
#pragma unroll
    for (int et = 0; et < 8; ++et) {
      f32x4 gg = *(const f32x4*)&sv[640 + et * 16 + lg * 4];
      f32x4 bb = *(const f32x4*)&sv[768 + et * 16 + lg * 4];
      f32x4 ww = *(const f32x4*)&sv[896 + et * 16 + lg * 4];
#pragma unroll
      for (int i = 0; i < 4; ++i) {
        float h2 = (oa[et][i] - mu2) * rs2 * gg[i] + bb[i];
        lp = fmaf(h2, ww[i], lp);
      }
    }
    lp += __shfl_xor(lp, 16);
    lp += __shfl_xor(lp, 32);
    if (lg == 0) {
      float sg = 1.f / (1.f + __expf(-(lp + bsj)));
      out[(long)(b0 + bloc) * NC + j] = sg;
    }
  }
}

extern "C" void kernel_launch(void* const* d_in, const int* in_sizes, int n_in,
                              void* d_out, int out_size, void* d_ws,
                              size_t ws_size, hipStream_t stream) {
  (void)in_sizes; (void)n_in; (void)out_size; (void)ws_size;
  const float* cat = (const float*)d_in[1];
  const float* emb = (const float*)d_in[2];
  const float* Wq = (const float*)d_in[3];
  const float* Wk = (const float*)d_in[4];
  const float* Wv = (const float*)d_in[5];
  const float* g1 = (const float*)d_in[6];
  const float* be1 = (const float*)d_in[7];
  const float* W1 = (const float*)d_in[8];
  const float* b1 = (const float*)d_in[9];
  const float* W2 = (const float*)d_in[10];
  const float* b2 = (const float*)d_in[11];
  const float* g2 = (const float*)d_in[12];
  const float* be2 = (const float*)d_in[13];
  const float* Ws = (const float*)d_in[14];
  const float* bs = (const float*)d_in[15];
  float* out = (float*)d_out;

  // workspace: 12 MB
  char* ws = (char*)d_ws;
  unsigned short* MtP = (unsigned short*)(ws);              // 2 MB swz [NC][256][128]
  unsigned short* VtP = (unsigned short*)(ws + (2 << 20));  // 2 MB swz [NC][128][256]
  unsigned short* W1tP = (unsigned short*)(ws + (4 << 20)); // 2 MB swz [NC][256][128]
  unsigned short* W2tP = (unsigned short*)(ws + (6 << 20)); // 2 MB swz [NC][128][256]
  float* Ktmp = (float*)(ws + (8 << 20));                   // 4 MB [NC][256][128]

  kv_kernel<<<NC * 8, 256, 0, stream>>>(emb, Wk, Wv, Ktmp, VtP);
  m_kernel<<<NC * 8, 256, 0, stream>>>(Wq, Ktmp, MtP);
  tr_kernel<<<2048, 256, 0, stream>>>(W1, W2, W1tP, W2tP);
  fused_kernel<<<2048, 256, 0, stream>>>(cat, MtP, VtP, W1tP, W2tP, b1, b2, g1,
                                         be1, g2, be2, Ws, bs, out);
}

// Round 6
// 137.923 us; speedup vs baseline: 2.2756x; 1.0746x over previous
//
#include <hip/hip_runtime.h>

// C2D_34419867910289 round 6 — register-resident activations.
// All GEMM->GEMM handoffs done via ds_bpermute lane redistribution (lg-axis
// only; b=lr ownership is shared by C-layout and B-fragment layout), so
// alpha/h1/ff never touch LDS. x loaded straight to fragments from global;
// x-residual re-fetched as float4; h1 residual kept as bf16 pairs.
// LDS 68->36KB -> 4 blocks/CU (launch_bounds(256,4)). f2b -> v_cvt_pk_bf16_f32.

typedef __attribute__((ext_vector_type(4))) float f32x4;
typedef __attribute__((ext_vector_type(8))) short bf16x8;
typedef __attribute__((ext_vector_type(4))) unsigned u32x4;

#define DEVI static __device__ __forceinline__
#define SB __builtin_amdgcn_sched_barrier(0)
#define BARR __builtin_amdgcn_s_barrier()
#define MEMF asm volatile("" ::: "memory")

constexpr int NC = 32, D = 128, C = 256, H = 256;

DEVI unsigned short f2b(float f) {  // RN-even float -> bf16 (prep kernels)
  unsigned u = __builtin_bit_cast(unsigned, f);
  u += 0x7fffu + ((u >> 16) & 1u);
  return (unsigned short)(u >> 16);
}
DEVI float b2f(unsigned short h) {
  unsigned u = ((unsigned)h) << 16;
  return __builtin_bit_cast(float, u);
}
DEVI unsigned pk2(float a, float b) {
  return (unsigned)f2b(a) | ((unsigned)f2b(b) << 16);
}
DEVI unsigned cvtpk(float a, float b) {  // v_cvt_pk_bf16_f32: lo=a, hi=b, RNE
  unsigned r;
  asm("v_cvt_pk_bf16_f32 %0, %1, %2" : "=v"(r) : "v"(a), "v"(b));
  return r;
}

template <int N> DEVI void vmwait() {
  asm volatile("s_waitcnt vmcnt(%0)" ::"n"(N) : "memory");
}
DEVI void lgkm0() { asm volatile("s_waitcnt lgkmcnt(0)" ::: "memory"); }

DEVI void gload16(const void* g, void* l) {
  __builtin_amdgcn_global_load_lds(
      (const __attribute__((address_space(1))) void*)g,
      (__attribute__((address_space(3))) void*)l, 16, 0, 0);
}

// Swizzle for all bf16 panels, keyed on row (8-row period):
//   byte = row*RB + ((slot ^ (row&7))<<4) + (elem&7)*2 ,  slot = col>>3

// ---------------- prep: K (fp32 tmp) and swizzled V^T (unchanged r5) -------
__global__ __launch_bounds__(256) void kv_kernel(
    const float* __restrict__ emb, const float* __restrict__ Wk,
    const float* __restrict__ Wv, float* __restrict__ Ktmp,
    unsigned short* __restrict__ VtP) {
  __shared__ float wk[D][D];
  __shared__ float wv[D][D];
  __shared__ float eb[32][D];
  const int j = blockIdx.x >> 3, ct = blockIdx.x & 7, tid = threadIdx.x;
  const float4* gk = (const float4*)(Wk + j * D * D);
  const float4* gv = (const float4*)(Wv + j * D * D);
  float4* lk = (float4*)&wk[0][0];
  float4* lv = (float4*)&wv[0][0];
  for (int i = tid; i < D * D / 4; i += 256) { lk[i] = gk[i]; lv[i] = gv[i]; }
  const float4* ge = (const float4*)(emb + (j * C + ct * 32) * D);
  float4* le = (float4*)&eb[0][0];
  for (int i = tid; i < 32 * D / 4; i += 256) le[i] = ge[i];
  __syncthreads();
  const int e = tid & 127, sel = tid >> 7;
  const float(*w)[D] = sel ? (const float(*)[D])wv : (const float(*)[D])wk;
  float acc[32];
#pragma unroll
  for (int r = 0; r < 32; ++r) acc[r] = 0.f;
  for (int d = 0; d < D; ++d) {
    float wde = w[d][e];
#pragma unroll
    for (int r = 0; r < 32; ++r) acc[r] = fmaf(eb[r][d], wde, acc[r]);
  }
  if (sel == 0) {
    for (int r = 0; r < 32; ++r) Ktmp[(j * C + ct * 32 + r) * D + e] = acc[r];
  } else {
#pragma unroll
    for (int k = 0; k < 4; ++k) {
      uint4 pk = {pk2(acc[k * 8 + 0], acc[k * 8 + 1]),
                  pk2(acc[k * 8 + 2], acc[k * 8 + 3]),
                  pk2(acc[k * 8 + 4], acc[k * 8 + 5]),
                  pk2(acc[k * 8 + 6], acc[k * 8 + 7])};
      int slot = (ct << 2) + k;
      long byte = (long)j * 65536 + e * 512 + ((slot ^ (e & 7)) << 4);
      *(uint4*)((char*)VtP + byte) = pk;
    }
  }
}

// ---- prep: MtP[c][d] = (1/sqrt(D)) * sum_e Wq[d][e]K[c][e] (unchanged) ----
__global__ __launch_bounds__(256) void m_kernel(
    const float* __restrict__ Wq, const float* __restrict__ Ktmp,
    unsigned short* __restrict__ MtP) {
  __shared__ float wqT[128][132];
  __shared__ float kt[32][129];
  const int j = blockIdx.x >> 3, ct = blockIdx.x & 7, tid = threadIdx.x;
  for (int i = tid; i < 128 * 32; i += 256) {
    int d = i >> 5, e4 = i & 31;
    float4 v = *(const float4*)(Wq + ((long)j * 128 + d) * 128 + e4 * 4);
    wqT[e4 * 4 + 0][d] = v.x; wqT[e4 * 4 + 1][d] = v.y;
    wqT[e4 * 4 + 2][d] = v.z; wqT[e4 * 4 + 3][d] = v.w;
  }
  for (int i = tid; i < 32 * 32; i += 256) {
    int r = i >> 5, c0 = (i & 31) * 4;
    float4 v = *(const float4*)(Ktmp + ((long)j * 256 + ct * 32 + r) * 128 + c0);
    kt[r][c0 + 0] = v.x; kt[r][c0 + 1] = v.y;
    kt[r][c0 + 2] = v.z; kt[r][c0 + 3] = v.w;
  }
  __syncthreads();
  const int cl = tid >> 3, s = tid & 7;
  float acc[16];
#pragma unroll
  for (int u = 0; u < 16; ++u) acc[u] = 0.f;
  for (int e = 0; e < 128; ++e) {
    float kk = kt[cl][e];
#pragma unroll
    for (int u = 0; u < 4; ++u) {
      float4 wv4 = *(const float4*)&wqT[e][s * 16 + u * 4];
      acc[u * 4 + 0] = fmaf(wv4.x, kk, acc[u * 4 + 0]);
      acc[u * 4 + 1] = fmaf(wv4.y, kk, acc[u * 4 + 1]);
      acc[u * 4 + 2] = fmaf(wv4.z, kk, acc[u * 4 + 2]);
      acc[u * 4 + 3] = fmaf(wv4.w, kk, acc[u * 4 + 3]);
    }
  }
  const float scale = 0.08838834764831845f;
  int c = ct * 32 + cl;
  uint4 pkA = {pk2(acc[0] * scale, acc[1] * scale),
               pk2(acc[2] * scale, acc[3] * scale),
               pk2(acc[4] * scale, acc[5] * scale),
               pk2(acc[6] * scale, acc[7] * scale)};
  uint4 pkB = {pk2(acc[8] * scale, acc[9] * scale),
               pk2(acc[10] * scale, acc[11] * scale),
               pk2(acc[12] * scale, acc[13] * scale),
               pk2(acc[14] * scale, acc[15] * scale)};
  long byteA = (long)j * 65536 + c * 256 + (((2 * s) ^ (c & 7)) << 4);
  long byteB = (long)j * 65536 + c * 256 + (((2 * s + 1) ^ (c & 7)) << 4);
  *(uint4*)((char*)MtP + byteA) = pkA;
  *(uint4*)((char*)MtP + byteB) = pkB;
}

// ---- prep: transposed + swizzled bf16 W1tP[h][d], W2tP[e][h] (unchanged) --
__global__ __launch_bounds__(256) void tr_kernel(
    const float* __restrict__ W1, const float* __restrict__ W2,
    unsigned short* __restrict__ W1tP, unsigned short* __restrict__ W2tP) {
  __shared__ float t[32][33];
  const int b = blockIdx.x;
  const bool isW2 = b >= 1024;
  const int bb = isW2 ? b - 1024 : b;
  const int j = bb >> 5, tile = bb & 31;
  const int tid = threadIdx.x, rr = tid >> 3, c4 = tid & 7;
  if (!isW2) {
    const int dt = tile & 3, ht = tile >> 2;
    float4 v = *(const float4*)(W1 + ((long)j * 128 + dt * 32 + rr) * 256 + ht * 32 + c4 * 4);
    t[rr][c4 * 4 + 0] = v.x; t[rr][c4 * 4 + 1] = v.y;
    t[rr][c4 * 4 + 2] = v.z; t[rr][c4 * 4 + 3] = v.w;
    __syncthreads();
    int row = ht * 32 + rr, colb = dt * 32 + c4 * 4;
    uint2 pk = {pk2(t[c4 * 4 + 0][rr], t[c4 * 4 + 1][rr]),
                pk2(t[c4 * 4 + 2][rr], t[c4 * 4 + 3][rr])};
    long byte = (long)j * 65536 + row * 256 + (((colb >> 3) ^ (row & 7)) << 4) + (colb & 7) * 2;
    *(uint2*)((char*)W1tP + byte) = pk;
  } else {
    const int et = tile & 3, ht = tile >> 2;
    float4 v = *(const float4*)(W2 + ((long)j * 256 + ht * 32 + rr) * 128 + et * 32 + c4 * 4);
    t[rr][c4 * 4 + 0] = v.x; t[rr][c4 * 4 + 1] = v.y;
    t[rr][c4 * 4 + 2] = v.z; t[rr][c4 * 4 + 3] = v.w;
    __syncthreads();
    int row = et * 32 + rr, colb = ht * 32 + c4 * 4;
    uint2 pk = {pk2(t[c4 * 4 + 0][rr], t[c4 * 4 + 1][rr]),
                pk2(t[c4 * 4 + 2][rr], t[c4 * 4 + 3][rr])};
    long byte = (long)j * 65536 + row * 512 + (((colb >> 3) ^ (row & 7)) << 4) + (colb & 7) * 2;
    *(uint2*)((char*)W2tP + byte) = pk;
  }
}

// ---------------- fused main kernel (register-resident activations) --------
// LDS: wb 2x16KB panel quarters + sv 4KB params = 36KB -> 4 blocks/CU.
// Redistribution C-layout -> B-fragment: et/ct/ht = 2*kc + (lg>>1),
// src lane lg' = 2*(lg&1) + (m>>2), i = m&3. 2 bpermute + 1 select per u32.
__global__ __launch_bounds__(256, 4) void fused_kernel(
    const float* __restrict__ x, const unsigned short* __restrict__ MtP,
    const unsigned short* __restrict__ VtP, const unsigned short* __restrict__ W1tP,
    const unsigned short* __restrict__ W2tP, const float* __restrict__ b1,
    const float* __restrict__ b2, const float* __restrict__ g1,
    const float* __restrict__ be1, const float* __restrict__ g2,
    const float* __restrict__ be2, const float* __restrict__ Ws,
    const float* __restrict__ bs, float* __restrict__ out) {
  __shared__ __align__(16) unsigned short wb[2][8192];
  __shared__ __align__(16) float sv[1024];
  const int bid = blockIdx.x;
  const int wg = (bid & 7) * 256 + (bid >> 3);  // XCD-chunked
  const int j = wg >> 6, b0 = (wg & 63) * 64;
  const int tid = threadIdx.x, w = tid >> 6, l = tid & 63, lr = l & 15, lg = l >> 4;
  const int bloc = w * 16 + lr;

  const unsigned short* pnl0 = MtP + (long)j * 32768;
  const unsigned short* pnl1 = VtP + (long)j * 32768;
  const unsigned short* pnl2 = W1tP + (long)j * 32768;
  const unsigned short* pnl3 = W2tP + (long)j * 32768;

  auto ISSUE = [&](int s2) {
    const unsigned short* base = (s2 < 4) ? pnl0 : (s2 < 8) ? pnl1 : (s2 < 12) ? pnl2 : pnl3;
    const char* gq = (const char*)(base + (s2 & 3) * 8192);
    char* lb = (char*)&wb[s2 & 1][0] + w * 4096;
    SB;
#pragma unroll
    for (int t = 0; t < 4; ++t)
      gload16(gq + (w * 4 + t) * 1024 + l * 16, lb + t * 1024);
    SB;
  };

  // ---- prologue ----
  const float* xrow = x + ((long)(b0 + bloc) * NC + j) * D;
  float4 xf[4][2];
#pragma unroll
  for (int kc = 0; kc < 4; ++kc) {
    xf[kc][0] = *(const float4*)(xrow + kc * 32 + lg * 8);
    xf[kc][1] = *(const float4*)(xrow + kc * 32 + lg * 8 + 4);
  }
  for (int i = tid; i < 1024; i += 256) {  // sv loads drain xf too (FIFO)
    float v;
    if (i < 256) v = b1[j * H + i];
    else if (i < 384) v = b2[j * D + i - 256];
    else if (i < 512) v = g1[i - 384];
    else if (i < 640) v = be1[i - 512];
    else if (i < 768) v = g2[i - 640];
    else if (i < 896) v = be2[i - 768];
    else v = Ws[j * D + i - 896];
    sv[i] = v;
  }
  SB;
  ISSUE(0);
  ISSUE(1);
  float bsj = bs[j];
  bf16x8 xa[4];
#pragma unroll
  for (int kc = 0; kc < 4; ++kc) {
    u32x4 t;
    t[0] = cvtpk(xf[kc][0].x, xf[kc][0].y);
    t[1] = cvtpk(xf[kc][0].z, xf[kc][0].w);
    t[2] = cvtpk(xf[kc][1].x, xf[kc][1].y);
    t[3] = cvtpk(xf[kc][1].z, xf[kc][1].w);
    xa[kc] = __builtin_bit_cast(bf16x8, t);
  }
  lgkm0(); SB; BARR; MEMF; SB;

  int inner[4], inner2[8];
#pragma unroll
  for (int kc = 0; kc < 4; ++kc)
    inner[kc] = lr * 256 + (((kc * 4 + lg) ^ (lr & 7)) << 4);
#pragma unroll
  for (int kc = 0; kc < 8; ++kc)
    inner2[kc] = lr * 512 + (((kc * 4 + lg) ^ (lr & 7)) << 4);

  const int ad0 = (((lg & 1) << 5) + lr) << 2;  // bpermute byte addr, half 0
  const int ad1 = ad0 + 64;                     // half 1
  const bool hi = (lg >> 1) != 0;

  bf16x8 aa[8];     // alpha fragments (GEMM2 B)
  bf16x8 xa2[4];    // h1 fragments (GEMM3 B)
  bf16x8 aa2[8];    // relu(ff1) fragments (GEMM4 B)
  unsigned hb[8][2];  // h1 bf16 pairs (LN2 residual)
  float4 xr[8];       // x residual (LN1)

  // ---- GEMM1: S^T = Mt @ x^T (stages 0..3) ----
  f32x4 sc[16];
#pragma unroll
  for (int t = 0; t < 16; ++t) sc[t] = (f32x4){0.f, 0.f, 0.f, 0.f};
#pragma unroll
  for (int q = 0; q < 4; ++q) {
    vmwait<4>(); SB; BARR; MEMF; SB;
    const char* wp = (const char*)wb[q & 1];
    __builtin_amdgcn_s_setprio(1);
#pragma unroll
    for (int c4 = 0; c4 < 4; ++c4)
#pragma unroll
      for (int kc = 0; kc < 4; ++kc) {
        bf16x8 bf = *(const bf16x8*)(wp + c4 * 4096 + inner[kc]);
        sc[q * 4 + c4] =
            __builtin_amdgcn_mfma_f32_16x16x32_bf16(bf, xa[kc], sc[q * 4 + c4], 0, 0, 0);
      }
    __builtin_amdgcn_s_setprio(0);
    if (q == 3) {
      // softmax over c: in-thread 64 + lg-reduce
      float mx = -1e30f;
#pragma unroll
      for (int ct = 0; ct < 16; ++ct)
#pragma unroll
        for (int i = 0; i < 4; ++i) mx = fmaxf(mx, sc[ct][i]);
      mx = fmaxf(mx, __shfl_xor(mx, 16));
      mx = fmaxf(mx, __shfl_xor(mx, 32));
      float sm = 0.f;
#pragma unroll
      for (int ct = 0; ct < 16; ++ct)
#pragma unroll
        for (int i = 0; i < 4; ++i) {
          float e = __expf(sc[ct][i] - mx);
          sc[ct][i] = e;
          sm += e;
        }
      sm += __shfl_xor(sm, 16);
      sm += __shfl_xor(sm, 32);
      float inv = 1.f / sm;
      unsigned au[16][2];
#pragma unroll
      for (int ct = 0; ct < 16; ++ct) {
        au[ct][0] = cvtpk(sc[ct][0] * inv, sc[ct][1] * inv);
        au[ct][1] = cvtpk(sc[ct][2] * inv, sc[ct][3] * inv);
      }
      // redistribute alpha -> aa[8]
#pragma unroll
      for (int kc = 0; kc < 8; ++kc) {
        u32x4 t;
#pragma unroll
        for (int h = 0; h < 2; ++h) {
          int ad = h ? ad1 : ad0;
#pragma unroll
          for (int p = 0; p < 2; ++p) {
            int f0 = __builtin_amdgcn_ds_bpermute(ad, (int)au[2 * kc][p]);
            int f1 = __builtin_amdgcn_ds_bpermute(ad, (int)au[2 * kc + 1][p]);
            t[h * 2 + p] = (unsigned)(hi ? f1 : f0);
          }
        }
        aa[kc] = __builtin_bit_cast(bf16x8, t);
      }
    }
    lgkm0(); SB; BARR; MEMF; SB;
    ISSUE(q + 2);
  }

  // ---- GEMM2: h^T = V^T @ alpha^T (stages 4..7) ----
  f32x4 ha[8];
#pragma unroll
  for (int t = 0; t < 8; ++t) ha[t] = (f32x4){0.f, 0.f, 0.f, 0.f};
#pragma unroll
  for (int q = 0; q < 4; ++q) {
    vmwait<4>(); SB; BARR; MEMF; SB;
    const char* wp = (const char*)wb[q & 1];
    __builtin_amdgcn_s_setprio(1);
#pragma unroll
    for (int e2 = 0; e2 < 2; ++e2)
#pragma unroll
      for (int kc = 0; kc < 8; ++kc) {
        bf16x8 bf = *(const bf16x8*)(wp + e2 * 8192 + inner2[kc]);
        ha[q * 2 + e2] =
            __builtin_amdgcn_mfma_f32_16x16x32_bf16(bf, aa[kc], ha[q * 2 + e2], 0, 0, 0);
      }
    __builtin_amdgcn_s_setprio(0);
    if (q == 2) {  // issue x-residual loads; drained by stage-7 vmwait<4>
#pragma unroll
      for (int et = 0; et < 8; ++et)
        xr[et] = *(const float4*)(xrow + et * 16 + lg * 4);
    }
    if (q == 3) {
      // residual + LN1 (f32 x), pack h1 -> hb, redistribute -> xa2
      float hvv[8][4];
      float s1 = 0.f, s2s = 0.f;
#pragma unroll
      for (int et = 0; et < 8; ++et)
#pragma unroll
        for (int i = 0; i < 4; ++i) {
          float v = ha[et][i] + xr[et][i];
          hvv[et][i] = v;
          s1 += v;
          s2s += v * v;
        }
      s1 += __shfl_xor(s1, 16); s2s += __shfl_xor(s2s, 16);
      s1 += __shfl_xor(s1, 32); s2s += __shfl_xor(s2s, 32);
      float mu = s1 * (1.f / 128.f);
      float var = s2s * (1.f / 128.f) - mu * mu;
      float rs = rsqrtf(var + 1e-5f);
#pragma unroll
      for (int et = 0; et < 8; ++et) {
        f32x4 gg = *(const f32x4*)&sv[384 + et * 16 + lg * 4];
        f32x4 bb = *(const f32x4*)&sv[512 + et * 16 + lg * 4];
        float h0 = (hvv[et][0] - mu) * rs * gg[0] + bb[0];
        float h1n = (hvv[et][1] - mu) * rs * gg[1] + bb[1];
        float h2 = (hvv[et][2] - mu) * rs * gg[2] + bb[2];
        float h3 = (hvv[et][3] - mu) * rs * gg[3] + bb[3];
        hb[et][0] = cvtpk(h0, h1n);
        hb[et][1] = cvtpk(h2, h3);
      }
#pragma unroll
      for (int kc = 0; kc < 4; ++kc) {
        u32x4 t;
#pragma unroll
        for (int h = 0; h < 2; ++h) {
          int ad = h ? ad1 : ad0;
#pragma unroll
          for (int p = 0; p < 2; ++p) {
            int f0 = __builtin_amdgcn_ds_bpermute(ad, (int)hb[2 * kc][p]);
            int f1 = __builtin_amdgcn_ds_bpermute(ad, (int)hb[2 * kc + 1][p]);
            t[h * 2 + p] = (unsigned)(hi ? f1 : f0);
          }
        }
        xa2[kc] = __builtin_bit_cast(bf16x8, t);
      }
    }
    lgkm0(); SB; BARR; MEMF; SB;
    ISSUE(6 + q);
  }

  // ---- GEMM3: ff^T = W1^T @ h1^T (stages 8..11) ----
  unsigned ffu[16][2];
#pragma unroll
  for (int q = 0; q < 4; ++q) {
    vmwait<4>(); SB; BARR; MEMF; SB;
    const char* wp = (const char*)wb[q & 1];
    f32x4 fa4[4];
#pragma unroll
    for (int t = 0; t < 4; ++t) fa4[t] = (f32x4){0.f, 0.f, 0.f, 0.f};
    __builtin_amdgcn_s_setprio(1);
#pragma unroll
    for (int c4 = 0; c4 < 4; ++c4)
#pragma unroll
      for (int kc = 0; kc < 4; ++kc) {
        bf16x8 bf = *(const bf16x8*)(wp + c4 * 4096 + inner[kc]);
        fa4[c4] =
            __builtin_amdgcn_mfma_f32_16x16x32_bf16(bf, xa2[kc], fa4[c4], 0, 0, 0);
      }
    __builtin_amdgcn_s_setprio(0);
#pragma unroll
    for (int c4 = 0; c4 < 4; ++c4) {  // relu + b1, pack
      int ht = q * 4 + c4;
      f32x4 bb = *(const f32x4*)&sv[ht * 16 + lg * 4];
      float v0 = fmaxf(fa4[c4][0] + bb[0], 0.f);
      float v1 = fmaxf(fa4[c4][1] + bb[1], 0.f);
      float v2 = fmaxf(fa4[c4][2] + bb[2], 0.f);
      float v3 = fmaxf(fa4[c4][3] + bb[3], 0.f);
      ffu[ht][0] = cvtpk(v0, v1);
      ffu[ht][1] = cvtpk(v2, v3);
    }
    if (q == 3) {  // redistribute ff -> aa2[8]
#pragma unroll
      for (int kc = 0; kc < 8; ++kc) {
        u32x4 t;
#pragma unroll
        for (int h = 0; h < 2; ++h) {
          int ad = h ? ad1 : ad0;
#pragma unroll
          for (int p = 0; p < 2; ++p) {
            int f0 = __builtin_amdgcn_ds_bpermute(ad, (int)ffu[2 * kc][p]);
            int f1 = __builtin_amdgcn_ds_bpermute(ad, (int)ffu[2 * kc + 1][p]);
            t[h * 2 + p] = (unsigned)(hi ? f1 : f0);
          }
        }
        aa2[kc] = __builtin_bit_cast(bf16x8, t);
      }
    }
    lgkm0(); SB; BARR; MEMF; SB;
    ISSUE(10 + q);
  }

  // ---- GEMM4: o^T = W2^T @ ff^T + LN2 + sigmoid (stages 12..15) ----
  f32x4 oa[8];
#pragma unroll
  for (int t = 0; t < 8; ++t) oa[t] = (f32x4){0.f, 0.f, 0.f, 0.f};
#pragma unroll
  for (int q = 0; q < 4; ++q) {
    if (q == 3) { vmwait<0>(); } else { vmwait<4>(); }
    SB; BARR; MEMF; SB;
    const char* wp = (const char*)wb[q & 1];
    __builtin_amdgcn_s_setprio(1);
#pragma unroll
    for (int e2 = 0; e2 < 2; ++e2)
#pragma unroll
      for (int kc = 0; kc < 8; ++kc) {
        bf16x8 bf = *(const bf16x8*)(wp + e2 * 8192 + inner2[kc]);
        oa[q * 2 + e2] =
            __builtin_amdgcn_mfma_f32_16x16x32_bf16(bf, aa2[kc], oa[q * 2 + e2], 0, 0, 0);
      }
    __builtin_amdgcn_s_setprio(0);
    if (q < 3) {
      lgkm0(); SB; BARR; MEMF; SB;
      if (q < 2) ISSUE(14 + q);
    }
  }
  // final epilogue: +b2 +h1(bf16), LN2, dot Ws, sigmoid
  {
    float t1 = 0.f, t2 = 0.f;
#pragma unroll
    for (int et = 0; et < 8; ++et) {
      f32x4 bb = *(const f32x4*)&sv[256 + et * 16 + lg * 4];
      float r0 = b2f((unsigned short)(hb[et][0] & 0xffff));
      float r1 = b2f((unsigned short)(hb[et][0] >> 16));
      float r2 = b2f((unsigned short)(hb[et][1] & 0xffff));
      float r3 = b2f((unsigned short)(hb[et][1] >> 16));
      float v0 = oa[et][0] + bb[0] + r0;
      float v1 = oa[et][1] + bb[1] + r1;
      float v2 = oa[et][2] + bb[2] + r2;
      float v3 = oa[et][3] + bb[3] + r3;
      oa[et][0] = v0; oa[et][1] = v1; oa[et][2] = v2; oa[et][3] = v3;
      t1 += (v0 + v1) + (v2 + v3);
      t2 += (v0 * v0 + v1 * v1) + (v2 * v2 + v3 * v3);
    }
    t1 += __shfl_xor(t1, 16); t2 += __shfl_xor(t2, 16);
    t1 += __shfl_xor(t1, 32); t2 += __shfl_xor(t2, 32);
    float mu2 = t1 * (1.f / 128.f);
    float var = t2 * (1.f / 128.f) - mu2 * mu2;
    float rs2 = rsqrtf(var + 1e-5f);
    float lp = 0.f;
#pragma unroll
    for (int et = 0; et < 8; ++et) {
      f32x4 gg = *(const f32x4*)&sv[640 + et * 16 + lg * 4];
      f32x4 bb = *(const f32x4*)&sv[768 + et * 16 + lg * 4];
      f32x4 ww = *(const f32x4*)&sv[896 + et * 16 + lg * 4];
#pragma unroll
      for (int i = 0; i < 4; ++i) {
        float h2 = (oa[et][i] - mu2) * rs2 * gg[i] + bb[i];
        lp = fmaf(h2, ww[i], lp);
      }
    }
    lp += __shfl_xor(lp, 16);
    lp += __shfl_xor(lp, 32);
    if (lg == 0) {
      float sg = 1.f / (1.f + __expf(-(lp + bsj)));
      out[(long)(b0 + bloc) * NC + j] = sg;
    }
  }
}

extern "C" void kernel_launch(void* const* d_in, const int* in_sizes, int n_in,
                              void* d_out, int out_size, void* d_ws,
                              size_t ws_size, hipStream_t stream) {
  (void)in_sizes; (void)n_in; (void)out_size; (void)ws_size;
  const float* cat = (const float*)d_in[1];
  const float* emb = (const float*)d_in[2];
  const float* Wq = (const float*)d_in[3];
  const float* Wk = (const float*)d_in[4];
  const float* Wv = (const float*)d_in[5];
  const float* g1 = (const float*)d_in[6];
  const float* be1 = (const float*)d_in[7];
  const float* W1 = (const float*)d_in[8];
  const float* b1 = (const float*)d_in[9];
  const float* W2 = (const float*)d_in[10];
  const float* b2 = (const float*)d_in[11];
  const float* g2 = (const float*)d_in[12];
  const float* be2 = (const float*)d_in[13];
  const float* Ws = (const float*)d_in[14];
  const float* bs = (const float*)d_in[15];
  float* out = (float*)d_out;

  // workspace: 12 MB
  char* ws = (char*)d_ws;
  unsigned short* MtP = (unsigned short*)(ws);              // 2 MB swz [NC][256][128]
  unsigned short* VtP = (unsigned short*)(ws + (2 << 20));  // 2 MB swz [NC][128][256]
  unsigned short* W1tP = (unsigned short*)(ws + (4 << 20)); // 2 MB swz [NC][256][128]
  unsigned short* W2tP = (unsigned short*)(ws + (6 << 20)); // 2 MB swz [NC][128][256]
  float* Ktmp = (float*)(ws + (8 << 20));                   // 4 MB [NC][256][128]

  kv_kernel<<<NC * 8, 256, 0, stream>>>(emb, Wk, Wv, Ktmp, VtP);
  m_kernel<<<NC * 8, 256, 0, stream>>>(Wq, Ktmp, MtP);
  tr_kernel<<<2048, 256, 0, stream>>>(W1, W2, W1tP, W2tP);
  fused_kernel<<<2048, 256, 0, stream>>>(cat, MtP, VtP, W1tP, W2tP, b1, b2, g1,
                                         be1, g2, be2, Ws, bs, out);
}

// Round 7
// 117.822 us; speedup vs baseline: 2.6638x; 1.1706x over previous
//
#include <hip/hip_runtime.h>

// C2D_34419867910289 round 7.
// Fused: 3-buffer panel rotation -> ONE barrier per stage + 2-deep counted
// vmcnt pipeline (vmwait<4> steady state). ISSUE before epilogues.
// Prep: kv+tr merged (role-split grid; K/V separate blocks @2/CU), m split
// along d (50KB LDS, 3/CU). 2 prep launches instead of 3.

typedef __attribute__((ext_vector_type(4))) float f32x4;
typedef __attribute__((ext_vector_type(8))) short bf16x8;
typedef __attribute__((ext_vector_type(4))) unsigned u32x4;

#define DEVI static __device__ __forceinline__
#define SB __builtin_amdgcn_sched_barrier(0)
#define BARR __builtin_amdgcn_s_barrier()
#define MEMF asm volatile("" ::: "memory")

constexpr int NC = 32, D = 128, C = 256, H = 256;

DEVI unsigned short f2b(float f) {  // RN-even float -> bf16 (prep)
  unsigned u = __builtin_bit_cast(unsigned, f);
  u += 0x7fffu + ((u >> 16) & 1u);
  return (unsigned short)(u >> 16);
}
DEVI float b2f(unsigned short h) {
  unsigned u = ((unsigned)h) << 16;
  return __builtin_bit_cast(float, u);
}
DEVI unsigned pk2(float a, float b) {
  return (unsigned)f2b(a) | ((unsigned)f2b(b) << 16);
}
DEVI unsigned cvtpk(float a, float b) {
  unsigned r;
  asm("v_cvt_pk_bf16_f32 %0, %1, %2" : "=v"(r) : "v"(a), "v"(b));
  return r;
}

template <int N> DEVI void vmwait() {
  asm volatile("s_waitcnt vmcnt(%0)" ::"n"(N) : "memory");
}
DEVI void lgkm0() { asm volatile("s_waitcnt lgkmcnt(0)" ::: "memory"); }

DEVI void gload16(const void* g, void* l) {
  __builtin_amdgcn_global_load_lds(
      (const __attribute__((address_space(1))) void*)g,
      (__attribute__((address_space(3))) void*)l, 16, 0, 0);
}

// Panel swizzle (8-row period): byte = row*RB + ((slot ^ (row&7))<<4) + (e&7)*2

// ---------------- prepA: K (fp32), swizzled V^T, W1t/W2t transposes --------
// bid<256: K(j,ct). 256..511: V(j,ct). 512..2559: transposes.
__global__ __launch_bounds__(256) void prepA_kernel(
    const float* __restrict__ emb, const float* __restrict__ Wk,
    const float* __restrict__ Wv, const float* __restrict__ W1,
    const float* __restrict__ W2, float* __restrict__ Ktmp,
    unsigned short* __restrict__ VtP, unsigned short* __restrict__ W1tP,
    unsigned short* __restrict__ W2tP) {
  __shared__ __align__(16) float smem[20480];  // 80KB
  const int bid = blockIdx.x, tid = threadIdx.x;
  if (bid < 512) {
    const bool isV = bid >= 256;
    const int bb = isV ? bid - 256 : bid;
    const int j = bb >> 3, ct = bb & 7;
    float* wm = smem;          // [128][128]
    float* eb = smem + 16384;  // [32][128]
    const float4* gw = (const float4*)((isV ? Wv : Wk) + (long)j * D * D);
    float4* lw = (float4*)wm;
    for (int i = tid; i < D * D / 4; i += 256) lw[i] = gw[i];
    const float4* ge = (const float4*)(emb + ((long)j * C + ct * 32) * D);
    float4* le = (float4*)eb;
    for (int i = tid; i < 32 * D / 4; i += 256) le[i] = ge[i];
    __syncthreads();
    const int e = tid & 127, h = tid >> 7;
    float acc[16];
#pragma unroll
    for (int r = 0; r < 16; ++r) acc[r] = 0.f;
    for (int d = 0; d < D; ++d) {
      float wde = wm[d * 128 + e];
#pragma unroll
      for (int r = 0; r < 16; ++r)
        acc[r] = fmaf(eb[(h * 16 + r) * 128 + d], wde, acc[r]);
    }
    if (!isV) {
      for (int r = 0; r < 16; ++r)
        Ktmp[((long)j * C + ct * 32 + h * 16 + r) * D + e] = acc[r];
    } else {
#pragma unroll
      for (int k = 0; k < 2; ++k) {
        uint4 pk = {pk2(acc[k * 8 + 0], acc[k * 8 + 1]),
                    pk2(acc[k * 8 + 2], acc[k * 8 + 3]),
                    pk2(acc[k * 8 + 4], acc[k * 8 + 5]),
                    pk2(acc[k * 8 + 6], acc[k * 8 + 7])};
        int slot = ct * 4 + h * 2 + k;
        long byte = (long)j * 65536 + e * 512 + ((slot ^ (e & 7)) << 4);
        *(uint4*)((char*)VtP + byte) = pk;
      }
    }
  } else {
    float(*t)[33] = reinterpret_cast<float(*)[33]>(smem);
    const int idx = bid - 512;
    const bool isW2 = idx >= 1024;
    const int bb = isW2 ? idx - 1024 : idx;
    const int j = bb >> 5, tile = bb & 31;
    const int rr = tid >> 3, c4 = tid & 7;
    if (!isW2) {
      const int dt = tile & 3, ht = tile >> 2;
      float4 v = *(const float4*)(W1 + ((long)j * 128 + dt * 32 + rr) * 256 + ht * 32 + c4 * 4);
      t[rr][c4 * 4 + 0] = v.x; t[rr][c4 * 4 + 1] = v.y;
      t[rr][c4 * 4 + 2] = v.z; t[rr][c4 * 4 + 3] = v.w;
      __syncthreads();
      int row = ht * 32 + rr, colb = dt * 32 + c4 * 4;
      uint2 pk = {pk2(t[c4 * 4 + 0][rr], t[c4 * 4 + 1][rr]),
                  pk2(t[c4 * 4 + 2][rr], t[c4 * 4 + 3][rr])};
      long byte = (long)j * 65536 + row * 256 + (((colb >> 3) ^ (row & 7)) << 4) + (colb & 7) * 2;
      *(uint2*)((char*)W1tP + byte) = pk;
    } else {
      const int et = tile & 3, ht = tile >> 2;
      float4 v = *(const float4*)(W2 + ((long)j * 256 + ht * 32 + rr) * 128 + et * 32 + c4 * 4);
      t[rr][c4 * 4 + 0] = v.x; t[rr][c4 * 4 + 1] = v.y;
      t[rr][c4 * 4 + 2] = v.z; t[rr][c4 * 4 + 3] = v.w;
      __syncthreads();
      int row = et * 32 + rr, colb = ht * 32 + c4 * 4;
      uint2 pk = {pk2(t[c4 * 4 + 0][rr], t[c4 * 4 + 1][rr]),
                  pk2(t[c4 * 4 + 2][rr], t[c4 * 4 + 3][rr])};
      long byte = (long)j * 65536 + row * 512 + (((colb >> 3) ^ (row & 7)) << 4) + (colb & 7) * 2;
      *(uint2*)((char*)W2tP + byte) = pk;
    }
  }
}

// ---- prepB: MtP[c][d] = (1/sqrt(D)) * sum_e Wq[d][e]K[c][e], d-split ------
__global__ __launch_bounds__(256) void prepB_kernel(
    const float* __restrict__ Wq, const float* __restrict__ Ktmp,
    unsigned short* __restrict__ MtP) {
  __shared__ float wqT[128][68];  // [e][dloc], dloc = d - dh*64
  __shared__ float kt[32][129];
  const int bid = blockIdx.x;
  const int j = bid >> 4, ct = (bid >> 1) & 7, dh = bid & 1;
  const int tid = threadIdx.x;
  for (int i = tid; i < 64 * 32; i += 256) {
    int dloc = i >> 5, e4 = i & 31;
    float4 v = *(const float4*)(Wq + ((long)j * 128 + dh * 64 + dloc) * 128 + e4 * 4);
    wqT[e4 * 4 + 0][dloc] = v.x; wqT[e4 * 4 + 1][dloc] = v.y;
    wqT[e4 * 4 + 2][dloc] = v.z; wqT[e4 * 4 + 3][dloc] = v.w;
  }
  for (int i = tid; i < 32 * 32; i += 256) {
    int r = i >> 5, c0 = (i & 31) * 4;
    float4 v = *(const float4*)(Ktmp + ((long)j * 256 + ct * 32 + r) * 128 + c0);
    kt[r][c0 + 0] = v.x; kt[r][c0 + 1] = v.y;
    kt[r][c0 + 2] = v.z; kt[r][c0 + 3] = v.w;
  }
  __syncthreads();
  const int cl = tid >> 3, s = tid & 7;
  float acc[8];
#pragma unroll
  for (int u = 0; u < 8; ++u) acc[u] = 0.f;
  for (int e = 0; e < 128; ++e) {
    float kk = kt[cl][e];
    float4 a = *(const float4*)&wqT[e][s * 8];
    float4 b = *(const float4*)&wqT[e][s * 8 + 4];
    acc[0] = fmaf(a.x, kk, acc[0]); acc[1] = fmaf(a.y, kk, acc[1]);
    acc[2] = fmaf(a.z, kk, acc[2]); acc[3] = fmaf(a.w, kk, acc[3]);
    acc[4] = fmaf(b.x, kk, acc[4]); acc[5] = fmaf(b.y, kk, acc[5]);
    acc[6] = fmaf(b.z, kk, acc[6]); acc[7] = fmaf(b.w, kk, acc[7]);
  }
  const float scale = 0.08838834764831845f;  // 1/sqrt(128)
  int c = ct * 32 + cl;
  uint4 pk = {pk2(acc[0] * scale, acc[1] * scale),
              pk2(acc[2] * scale, acc[3] * scale),
              pk2(acc[4] * scale, acc[5] * scale),
              pk2(acc[6] * scale, acc[7] * scale)};
  int slot = dh * 8 + s;
  long byte = (long)j * 65536 + c * 256 + ((slot ^ (c & 7)) << 4);
  *(uint4*)((char*)MtP + byte) = pk;
}

// ---------------- fused main kernel (3-buffer, 1 barrier/stage) ------------
__global__ __launch_bounds__(256, 3) void fused_kernel(
    const float* __restrict__ x, const unsigned short* __restrict__ MtP,
    const unsigned short* __restrict__ VtP, const unsigned short* __restrict__ W1tP,
    const unsigned short* __restrict__ W2tP, const float* __restrict__ b1,
    const float* __restrict__ b2, const float* __restrict__ g1,
    const float* __restrict__ be1, const float* __restrict__ g2,
    const float* __restrict__ be2, const float* __restrict__ Ws,
    const float* __restrict__ bs, float* __restrict__ out) {
  __shared__ __align__(16) unsigned short wb[3][8192];  // 48KB
  __shared__ __align__(16) float sv[1024];              // 4KB
  const int bid = blockIdx.x;
  const int wg = (bid & 7) * 256 + (bid >> 3);  // XCD-chunked
  const int j = wg >> 6, b0 = (wg & 63) * 64;
  const int tid = threadIdx.x, w = tid >> 6, l = tid & 63, lr = l & 15, lg = l >> 4;
  const int bloc = w * 16 + lr;

  const unsigned short* pnl0 = MtP + (long)j * 32768;
  const unsigned short* pnl1 = VtP + (long)j * 32768;
  const unsigned short* pnl2 = W1tP + (long)j * 32768;
  const unsigned short* pnl3 = W2tP + (long)j * 32768;

  auto ISSUE = [&](int s2) {
    const unsigned short* base = (s2 < 4) ? pnl0 : (s2 < 8) ? pnl1 : (s2 < 12) ? pnl2 : pnl3;
    const char* gq = (const char*)(base + (s2 & 3) * 8192);
    char* lb = (char*)&wb[s2 % 3][0] + w * 4096;
    SB;
#pragma unroll
    for (int t = 0; t < 4; ++t)
      gload16(gq + (w * 4 + t) * 1024 + l * 16, lb + t * 1024);
    SB;
  };

  // ---- prologue ----
  const float* xrow = x + ((long)(b0 + bloc) * NC + j) * D;
  float4 xf[4][2];
#pragma unroll
  for (int kc = 0; kc < 4; ++kc) {
    xf[kc][0] = *(const float4*)(xrow + kc * 32 + lg * 8);
    xf[kc][1] = *(const float4*)(xrow + kc * 32 + lg * 8 + 4);
  }
  for (int i = tid; i < 1024; i += 256) {
    float v;
    if (i < 256) v = b1[j * H + i];
    else if (i < 384) v = b2[j * D + i - 256];
    else if (i < 512) v = g1[i - 384];
    else if (i < 640) v = be1[i - 512];
    else if (i < 768) v = g2[i - 640];
    else if (i < 896) v = be2[i - 768];
    else v = Ws[j * D + i - 896];
    sv[i] = v;
  }
  SB;
  ISSUE(0);
  ISSUE(1);
  float bsj = bs[j];
  bf16x8 xa[4];
#pragma unroll
  for (int kc = 0; kc < 4; ++kc) {
    u32x4 t;
    t[0] = cvtpk(xf[kc][0].x, xf[kc][0].y);
    t[1] = cvtpk(xf[kc][0].z, xf[kc][0].w);
    t[2] = cvtpk(xf[kc][1].x, xf[kc][1].y);
    t[3] = cvtpk(xf[kc][1].z, xf[kc][1].w);
    xa[kc] = __builtin_bit_cast(bf16x8, t);
  }
  lgkm0(); SB; BARR; MEMF; SB;

  int inner[4], inner2[8];
#pragma unroll
  for (int kc = 0; kc < 4; ++kc)
    inner[kc] = lr * 256 + (((kc * 4 + lg) ^ (lr & 7)) << 4);
#pragma unroll
  for (int kc = 0; kc < 8; ++kc)
    inner2[kc] = lr * 512 + (((kc * 4 + lg) ^ (lr & 7)) << 4);

  const int ad0 = (((lg & 1) << 5) + lr) << 2;
  const int ad1 = ad0 + 64;
  const bool hi = (lg >> 1) != 0;

  bf16x8 aa[8], xa2[4], aa2[8];
  unsigned hb[8][2];
  float4 xr[8];

  // ---- GEMM1: S^T = Mt @ x^T (stages 0..3) ----
  f32x4 sc[16];
#pragma unroll
  for (int t = 0; t < 16; ++t) sc[t] = (f32x4){0.f, 0.f, 0.f, 0.f};
#pragma unroll
  for (int q = 0; q < 4; ++q) {
    vmwait<4>(); SB; BARR; MEMF; SB;
    const char* wp = (const char*)wb[q % 3];
    __builtin_amdgcn_s_setprio(1);
#pragma unroll
    for (int c4 = 0; c4 < 4; ++c4)
#pragma unroll
      for (int kc = 0; kc < 4; ++kc) {
        bf16x8 bf = *(const bf16x8*)(wp + c4 * 4096 + inner[kc]);
        sc[q * 4 + c4] =
            __builtin_amdgcn_mfma_f32_16x16x32_bf16(bf, xa[kc], sc[q * 4 + c4], 0, 0, 0);
      }
    __builtin_amdgcn_s_setprio(0);
    ISSUE(q + 2);
    if (q == 3) {
      float mx = -1e30f;
#pragma unroll
      for (int ct = 0; ct < 16; ++ct)
#pragma unroll
        for (int i = 0; i < 4; ++i) mx = fmaxf(mx, sc[ct][i]);
      mx = fmaxf(mx, __shfl_xor(mx, 16));
      mx = fmaxf(mx, __shfl_xor(mx, 32));
      float sm = 0.f;
#pragma unroll
      for (int ct = 0; ct < 16; ++ct)
#pragma unroll
        for (int i = 0; i < 4; ++i) {
          float e = __expf(sc[ct][i] - mx);
          sc[ct][i] = e;
          sm += e;
        }
      sm += __shfl_xor(sm, 16);
      sm += __shfl_xor(sm, 32);
      float inv = 1.f / sm;
      unsigned au[16][2];
#pragma unroll
      for (int ct = 0; ct < 16; ++ct) {
        au[ct][0] = cvtpk(sc[ct][0] * inv, sc[ct][1] * inv);
        au[ct][1] = cvtpk(sc[ct][2] * inv, sc[ct][3] * inv);
      }
#pragma unroll
      for (int kc = 0; kc < 8; ++kc) {
        u32x4 t;
#pragma unroll
        for (int h = 0; h < 2; ++h) {
          int ad = h ? ad1 : ad0;
#pragma unroll
          for (int p = 0; p < 2; ++p) {
            int f0 = __builtin_amdgcn_ds_bpermute(ad, (int)au[2 * kc][p]);
            int f1 = __builtin_amdgcn_ds_bpermute(ad, (int)au[2 * kc + 1][p]);
            t[h * 2 + p] = (unsigned)(hi ? f1 : f0);
          }
        }
        aa[kc] = __builtin_bit_cast(bf16x8, t);
      }
    }
  }

  // ---- GEMM2: h^T = V^T @ alpha^T (stages 4..7) ----
  f32x4 ha[8];
#pragma unroll
  for (int t = 0; t < 8; ++t) ha[t] = (f32x4){0.f, 0.f, 0.f, 0.f};
#pragma unroll
  for (int q = 0; q < 4; ++q) {
    vmwait<4>(); SB; BARR; MEMF; SB;
    const char* wp = (const char*)wb[(4 + q) % 3];
    __builtin_amdgcn_s_setprio(1);
#pragma unroll
    for (int e2 = 0; e2 < 2; ++e2)
#pragma unroll
      for (int kc = 0; kc < 8; ++kc) {
        bf16x8 bf = *(const bf16x8*)(wp + e2 * 8192 + inner2[kc]);
        ha[q * 2 + e2] =
            __builtin_amdgcn_mfma_f32_16x16x32_bf16(bf, aa[kc], ha[q * 2 + e2], 0, 0, 0);
      }
    __builtin_amdgcn_s_setprio(0);
    if (q == 2) {  // x-residual loads: drained by stage-7 vmwait<4>
#pragma unroll
      for (int et = 0; et < 8; ++et)
        xr[et] = *(const float4*)(xrow + et * 16 + lg * 4);
    }
    ISSUE(6 + q);
    if (q == 3) {
      float hvv[8][4];
      float s1 = 0.f, s2s = 0.f;
#pragma unroll
      for (int et = 0; et < 8; ++et)
#pragma unroll
        for (int i = 0; i < 4; ++i) {
          float v = ha[et][i] + xr[et][i];
          hvv[et][i] = v;
          s1 += v;
          s2s += v * v;
        }
      s1 += __shfl_xor(s1, 16); s2s += __shfl_xor(s2s, 16);
      s1 += __shfl_xor(s1, 32); s2s += __shfl_xor(s2s, 32);
      float mu = s1 * (1.f / 128.f);
      float var = s2s * (1.f / 128.f) - mu * mu;
      float rs = rsqrtf(var + 1e-5f);
#pragma unroll
      for (int et = 0; et < 8; ++et) {
        f32x4 gg = *(const f32x4*)&sv[384 + et * 16 + lg * 4];
        f32x4 bb = *(const f32x4*)&sv[512 + et * 16 + lg * 4];
        float h0 = (hvv[et][0] - mu) * rs * gg[0] + bb[0];
        float h1n = (hvv[et][1] - mu) * rs * gg[1] + bb[1];
        float h2 = (hvv[et][2] - mu) * rs * gg[2] + bb[2];
        float h3 = (hvv[et][3] - mu) * rs * gg[3] + bb[3];
        hb[et][0] = cvtpk(h0, h1n);
        hb[et][1] = cvtpk(h2, h3);
      }
#pragma unroll
      for (int kc = 0; kc < 4; ++kc) {
        u32x4 t;
#pragma unroll
        for (int h = 0; h < 2; ++h) {
          int ad = h ? ad1 : ad0;
#pragma unroll
          for (int p = 0; p < 2; ++p) {
            int f0 = __builtin_amdgcn_ds_bpermute(ad, (int)hb[2 * kc][p]);
            int f1 = __builtin_amdgcn_ds_bpermute(ad, (int)hb[2 * kc + 1][p]);
            t[h * 2 + p] = (unsigned)(hi ? f1 : f0);
          }
        }
        xa2[kc] = __builtin_bit_cast(bf16x8, t);
      }
    }
  }

  // ---- GEMM3: ff^T = W1^T @ h1^T (stages 8..11) ----
  unsigned ffu[16][2];
#pragma unroll
  for (int q = 0; q < 4; ++q) {
    vmwait<4>(); SB; BARR; MEMF; SB;
    const char* wp = (const char*)wb[(8 + q) % 3];
    f32x4 fa4[4];
#pragma unroll
    for (int t = 0; t < 4; ++t) fa4[t] = (f32x4){0.f, 0.f, 0.f, 0.f};
    __builtin_amdgcn_s_setprio(1);
#pragma unroll
    for (int c4 = 0; c4 < 4; ++c4)
#pragma unroll
      for (int kc = 0; kc < 4; ++kc) {
        bf16x8 bf = *(const bf16x8*)(wp + c4 * 4096 + inner[kc]);
        fa4[c4] =
            __builtin_amdgcn_mfma_f32_16x16x32_bf16(bf, xa2[kc], fa4[c4], 0, 0, 0);
      }
    __builtin_amdgcn_s_setprio(0);
    ISSUE(10 + q);
#pragma unroll
    for (int c4 = 0; c4 < 4; ++c4) {
      int ht = q * 4 + c4;
      f32x4 bb = *(const f32x4*)&sv[ht * 16 + lg * 4];
      float v0 = fmaxf(fa4[c4][0] + bb[0], 0.f);
      float v1 = fmaxf(fa4[c4][1] + bb[1], 0.f);
      float v2 = fmaxf(fa4[c4][2] + bb[2], 0.f);
      float v3 = fmaxf(fa4[c4][3] + bb[3], 0.f);
      ffu[ht][0] = cvtpk(v0, v1);
      ffu[ht][1] = cvtpk(v2, v3);
    }
    if (q == 3) {
#pragma unroll
      for (int kc = 0; kc < 8; ++kc) {
        u32x4 t;
#pragma unroll
        for (int h = 0; h < 2; ++h) {
          int ad = h ? ad1 : ad0;
#pragma unroll
          for (int p = 0; p < 2; ++p) {
            int f0 = __builtin_amdgcn_ds_bpermute(ad, (int)ffu[2 * kc][p]);
            int f1 = __builtin_amdgcn_ds_bpermute(ad, (int)ffu[2 * kc + 1][p]);
            t[h * 2 + p] = (unsigned)(hi ? f1 : f0);
          }
        }
        aa2[kc] = __builtin_bit_cast(bf16x8, t);
      }
    }
  }

  // ---- GEMM4: o^T = W2^T @ ff^T (stages 12..15) ----
  f32x4 oa[8];
#pragma unroll
  for (int t = 0; t < 8; ++t) oa[t] = (f32x4){0.f, 0.f, 0.f, 0.f};
#pragma unroll
  for (int q = 0; q < 4; ++q) {
    if (q == 3) { vmwait<0>(); } else { vmwait<4>(); }
    SB; BARR; MEMF; SB;
    const char* wp = (const char*)wb[(12 + q) % 3];
    __builtin_amdgcn_s_setprio(1);
#pragma unroll
    for (int e2 = 0; e2 < 2; ++e2)
#pragma unroll
      for (int kc = 0; kc < 8; ++kc) {
        bf16x8 bf = *(const bf16x8*)(wp + e2 * 8192 + inner2[kc]);
        oa[q * 2 + e2] =
            __builtin_amdgcn_mfma_f32_16x16x32_bf16(bf, aa2[kc], oa[q * 2 + e2], 0, 0, 0);
      }
    __builtin_amdgcn_s_setprio(0);
    if (q < 2) ISSUE(14 + q);
  }
  // final epilogue: +b2 +h1(bf16), LN2, dot Ws, sigmoid
  {
    float t1 = 0.f, t2 = 0.f;
#pragma unroll
    for (int et = 0; et < 8; ++et) {
      f32x4 bb = *(const f32x4*)&sv[256 + et * 16 + lg * 4];
      float r0 = b2f((unsigned short)(hb[et][0] & 0xffff));
      float r1 = b2f((unsigned short)(hb[et][0] >> 16));
      float r2 = b2f((unsigned short)(hb[et][1] & 0xffff));
      float r3 = b2f((unsigned short)(hb[et][1] >> 16));
      float v0 = oa[et][0] + bb[0] + r0;
      float v1 = oa[et][1] + bb[1] + r1;
      float v2 = oa[et][2] + bb[2] + r2;
      float v3 = oa[et][3] + bb[3] + r3;
      oa[et][0] = v0; oa[et][1] = v1; oa[et][2] = v2; oa[et][3] = v3;
      t1 += (v0 + v1) + (v2 + v3);
      t2 += (v0 * v0 + v1 * v1) + (v2 * v2 + v3 * v3);
    }
    t1 += __shfl_xor(t1, 16); t2 += __shfl_xor(t2, 16);
    t1 += __shfl_xor(t1, 32); t2 += __shfl_xor(t2, 32);
    float mu2 = t1 * (1.f / 128.f);
    float var = t2 * (1.f / 128.f) - mu2 * mu2;
    float rs2 = rsqrtf(var + 1e-5f);
    float lp = 0.f;
#pragma unroll
    for (int et = 0; et < 8; ++et) {
      f32x4 gg = *(const f32x4*)&sv[640 + et * 16 + lg * 4];
      f32x4 bb = *(const f32x4*)&sv[768 + et * 16 + lg * 4];
      f32x4 ww = *(const f32x4*)&sv[896 + et * 16 + lg * 4];
#pragma unroll
      for (int i = 0; i < 4; ++i) {
        float h2 = (oa[et][i] - mu2) * rs2 * gg[i] + bb[i];
        lp = fmaf(h2, ww[i], lp);
      }
    }
    lp += __shfl_xor(lp, 16);
    lp += __shfl_xor(lp, 32);
    if (lg == 0) {
      float sg = 1.f / (1.f + __expf(-(lp + bsj)));
      out[(long)(b0 + bloc) * NC + j] = sg;
    }
  }
}

extern "C" void kernel_launch(void* const* d_in, const int* in_sizes, int n_in,
                              void* d_out, int out_size, void* d_ws,
                              size_t ws_size, hipStream_t stream) {
  (void)in_sizes; (void)n_in; (void)out_size; (void)ws_size;
  const float* cat = (const float*)d_in[1];
  const float* emb = (const float*)d_in[2];
  const float* Wq = (const float*)d_in[3];
  const float* Wk = (const float*)d_in[4];
  const float* Wv = (const float*)d_in[5];
  const float* g1 = (const float*)d_in[6];
  const float* be1 = (const float*)d_in[7];
  const float* W1 = (const float*)d_in[8];
  const float* b1 = (const float*)d_in[9];
  const float* W2 = (const float*)d_in[10];
  const float* b2 = (const float*)d_in[11];
  const float* g2 = (const float*)d_in[12];
  const float* be2 = (const float*)d_in[13];
  const float* Ws = (const float*)d_in[14];
  const float* bs = (const float*)d_in[15];
  float* out = (float*)d_out;

  // workspace: 12 MB
  char* ws = (char*)d_ws;
  unsigned short* MtP = (unsigned short*)(ws);              // 2 MB swz [NC][256][128]
  unsigned short* VtP = (unsigned short*)(ws + (2 << 20));  // 2 MB swz [NC][128][256]
  unsigned short* W1tP = (unsigned short*)(ws + (4 << 20)); // 2 MB swz [NC][256][128]
  unsigned short* W2tP = (unsigned short*)(ws + (6 << 20)); // 2 MB swz [NC][128][256]
  float* Ktmp = (float*)(ws + (8 << 20));                   // 4 MB [NC][256][128]

  prepA_kernel<<<2560, 256, 0, stream>>>(emb, Wk, Wv, W1, W2, Ktmp, VtP, W1tP, W2tP);
  prepB_kernel<<<512, 256, 0, stream>>>(Wq, Ktmp, MtP);
  fused_kernel<<<2048, 256, 0, stream>>>(cat, MtP, VtP, W1tP, W2tP, b1, b2, g1,
                                         be1, g2, be2, Ws, bs, out);
}